// Round 2
// baseline (794.724 us; speedup 1.0000x reference)
//
#include <hip/hip_runtime.h>
#include <math.h>

#define B_  2
#define S_  2048
#define D_  1024
#define H_  16
#define DH  64
#define M_  (B_*S_)     // 4096
#define QKSZ 4194304    // B*H*S*DH

typedef __attribute__((ext_vector_type(4))) float  f32x4;
typedef __attribute__((ext_vector_type(8))) short  short8;
typedef __attribute__((ext_vector_type(8))) unsigned short ushort8;

static __device__ __forceinline__ unsigned short f2bf(float x) {
    union { float f; unsigned int u; } v; v.f = x;
    unsigned int u = v.u;
    u += 0x7fffu + ((u >> 16) & 1u);   // round-to-nearest-even
    return (unsigned short)(u >> 16);
}

// ---------------------------------------------------------------------------
// Kernel 1: fused QKV projection (fp32) + RoPE, writes bf16 q,k ([bh][s][dh])
// and transposed v ([bh][dh][s]).
// C[m,n] = sum_k hid[m,k] * W[n,k];  n in [0,3072): 0-1023 Q, 1024-2047 K, else V
// ---------------------------------------------------------------------------
#define TM 128
#define TN 128
#define TK 32
#define LDP (TK + 1)   // 33 floats: 4-way-max bank spread on micro-tile reads

__global__ __launch_bounds__(256) void qkv_proj(
    const float* __restrict__ hid,
    const float* __restrict__ sp,     // (S,64): [:,0:32]=sin, [:,32:64]=cos
    const float* __restrict__ Wq,
    const float* __restrict__ Wk,
    const float* __restrict__ Wv,
    unsigned short* __restrict__ qk_ws,   // q then k, each QKSZ bf16
    unsigned short* __restrict__ vt_ws)   // (B*H, DH, S) bf16
{
    __shared__ float As[TM * LDP];
    __shared__ float Bs[TN * LDP];

    const int tid    = threadIdx.x;
    const int tile_m = (blockIdx.x & 31) * TM;   // 32 m-tiles
    const int tile_n = (blockIdx.x >> 5) * TN;   // 24 n-tiles

    const float* W; int nloc;
    if (tile_n < 1024)      { W = Wq; nloc = tile_n; }
    else if (tile_n < 2048) { W = Wk; nloc = tile_n - 1024; }
    else                    { W = Wv; nloc = tile_n - 2048; }

    const int ty = tid >> 4, tx = tid & 15;
    const int frow = tid >> 3;          // 0..31
    const int fcol = (tid & 7) * 4;     // 0,4,..,28

    float acc[8][8];
    #pragma unroll
    for (int i = 0; i < 8; ++i)
        #pragma unroll
        for (int j = 0; j < 8; ++j) acc[i][j] = 0.f;

    for (int k0 = 0; k0 < D_; k0 += TK) {
        #pragma unroll
        for (int p = 0; p < 4; ++p) {
            int row = p * 32 + frow;
            float4 a = *(const float4*)&hid[(size_t)(tile_m + row) * D_ + k0 + fcol];
            float4 b = *(const float4*)&W  [(size_t)(nloc   + row) * D_ + k0 + fcol];
            As[row * LDP + fcol + 0] = a.x; As[row * LDP + fcol + 1] = a.y;
            As[row * LDP + fcol + 2] = a.z; As[row * LDP + fcol + 3] = a.w;
            Bs[row * LDP + fcol + 0] = b.x; Bs[row * LDP + fcol + 1] = b.y;
            Bs[row * LDP + fcol + 2] = b.z; Bs[row * LDP + fcol + 3] = b.w;
        }
        __syncthreads();
        #pragma unroll 8
        for (int kk = 0; kk < TK; ++kk) {
            float a[8], b[8];
            #pragma unroll
            for (int i = 0; i < 8; ++i) a[i] = As[(ty * 8 + i) * LDP + kk];
            #pragma unroll
            for (int j = 0; j < 8; ++j) b[j] = Bs[(tx * 8 + j) * LDP + kk];
            #pragma unroll
            for (int i = 0; i < 8; ++i)
                #pragma unroll
                for (int j = 0; j < 8; ++j) acc[i][j] += a[i] * b[j];
        }
        __syncthreads();
    }

    const int nbase = tile_n + tx * 8;
    if (tile_n < 2048) {
        const int isK  = (tile_n >= 1024) ? 1 : 0;
        const int nq   = nbase - (isK ? 1024 : 0);   // 0..1023
        const int head = nq >> 6;
        const int dh0  = nq & 63;                    // multiple of 8
        const int pb   = dh0 >> 1;                   // pair base, multiple of 4
        unsigned short* base = qk_ws + (size_t)isK * QKSZ;
        #pragma unroll
        for (int i = 0; i < 8; ++i) {
            int m = tile_m + ty * 8 + i;
            int b = m >> 11, s = m & 2047;
            float4 sv = *(const float4*)&sp[s * 64 + pb];
            float4 cv = *(const float4*)&sp[s * 64 + 32 + pb];
            short8 o;
            float e0 = acc[i][0], o0 = acc[i][1], e1 = acc[i][2], o1 = acc[i][3];
            float e2 = acc[i][4], o2 = acc[i][5], e3 = acc[i][6], o3 = acc[i][7];
            o[0] = (short)f2bf(e0 * cv.x - o0 * sv.x); o[1] = (short)f2bf(o0 * cv.x + e0 * sv.x);
            o[2] = (short)f2bf(e1 * cv.y - o1 * sv.y); o[3] = (short)f2bf(o1 * cv.y + e1 * sv.y);
            o[4] = (short)f2bf(e2 * cv.z - o2 * sv.z); o[5] = (short)f2bf(o2 * cv.z + e2 * sv.z);
            o[6] = (short)f2bf(e3 * cv.w - o3 * sv.w); o[7] = (short)f2bf(o3 * cv.w + e3 * sv.w);
            *(short8*)&base[((size_t)(b * H_ + head) * S_ + s) * DH + dh0] = o;
        }
    } else {
        const int nv   = nbase - 2048;
        const int head = nv >> 6;
        const int dh0  = nv & 63;
        const int m0   = tile_m + ty * 8;
        const int b    = m0 >> 11, s0 = m0 & 2047;   // s0 multiple of 8
        unsigned short* vb = vt_ws + (size_t)(b * H_ + head) * DH * S_;
        #pragma unroll
        for (int j = 0; j < 8; ++j) {
            ushort8 o;
            #pragma unroll
            for (int i = 0; i < 8; ++i) o[i] = f2bf(acc[i][j]);
            *(ushort8*)&vb[(dh0 + j) * S_ + s0] = o;
        }
    }
}

// ---------------------------------------------------------------------------
// Kernel 2: flash attention, bf16 MFMA 16x16x32, fp32 accum.
// Block = 4 waves; wave w owns 16 q-rows; KV tile = 64.
// ---------------------------------------------------------------------------
__global__ __launch_bounds__(256) void attn_fwd(
    const unsigned short* __restrict__ qk_ws,
    const unsigned short* __restrict__ vt_ws,
    const float* __restrict__ maskp,   // (B, S)
    float* __restrict__ out)           // (B, S, D)
{
    __shared__ unsigned short Pl[4][16 * 64];   // per-wave P buffer (XOR-swizzled)

    const int tid  = threadIdx.x;
    const int w    = tid >> 6, lane = tid & 63;
    const int g    = lane >> 4, c16 = lane & 15;
    const int qt   = blockIdx.x & 31;
    const int bh   = blockIdx.x >> 5;          // 0..31
    const int b    = bh >> 4, h = bh & 15;

    const unsigned short* qp = qk_ws + (size_t)bh * (S_ * DH);
    const unsigned short* kp = qk_ws + QKSZ + (size_t)bh * (S_ * DH);
    const unsigned short* vp = vt_ws + (size_t)bh * (DH * S_);
    const float* mp = maskp + b * S_;
    const int q0 = qt * 64 + w * 16;

    // Q fragments: A[i=q][k=dh], i=c16, k=8g+e (+32c)
    short8 qf[2];
    #pragma unroll
    for (int c = 0; c < 2; ++c)
        qf[c] = *(const short8*)&qp[(size_t)(q0 + c16) * DH + 32 * c + 8 * g];

    f32x4 ctx[4];
    float mrow[4], lrow[4];
    #pragma unroll
    for (int t = 0; t < 4; ++t) { ctx[t][0] = ctx[t][1] = ctx[t][2] = ctx[t][3] = 0.f; }
    #pragma unroll
    for (int r = 0; r < 4; ++r) { mrow[r] = -1e30f; lrow[r] = 0.f; }

    unsigned short* pl = &Pl[w][0];

    for (int kv = 0; kv < S_; kv += 64) {
        // ---- QK^T: D[q][key], 4 key-tiles of 16 ----
        f32x4 sa[4];
        #pragma unroll
        for (int t = 0; t < 4; ++t) { sa[t][0] = sa[t][1] = sa[t][2] = sa[t][3] = 0.f; }
        #pragma unroll
        for (int t = 0; t < 4; ++t)
            #pragma unroll
            for (int c = 0; c < 2; ++c)
                sa[t] = __builtin_amdgcn_mfma_f32_16x16x32_bf16(
                    qf[c],
                    *(const short8*)&kp[(size_t)(kv + 16 * t + c16) * DH + 32 * c + 8 * g],
                    sa[t], 0, 0, 0);

        float sc[4][4];
        #pragma unroll
        for (int t = 0; t < 4; ++t) {
            float mv = mp[kv + 16 * t + c16];
            #pragma unroll
            for (int r = 0; r < 4; ++r) sc[t][r] = sa[t][r] * 0.125f + mv;
        }

        // ---- online softmax (row = q0 + 4g + r; full row in this 16-lane group) ----
        float fac[4];
        #pragma unroll
        for (int r = 0; r < 4; ++r) {
            float v = fmaxf(fmaxf(sc[0][r], sc[1][r]), fmaxf(sc[2][r], sc[3][r]));
            v = fmaxf(v, __shfl_xor(v, 1));
            v = fmaxf(v, __shfl_xor(v, 2));
            v = fmaxf(v, __shfl_xor(v, 4));
            v = fmaxf(v, __shfl_xor(v, 8));
            float nm = fmaxf(mrow[r], v);
            fac[r] = __expf(mrow[r] - nm);
            mrow[r] = nm;
            lrow[r] *= fac[r];
        }
        #pragma unroll
        for (int t = 0; t < 4; ++t)
            #pragma unroll
            for (int r = 0; r < 4; ++r) ctx[t][r] *= fac[r];

        // ---- P -> LDS (D-layout write, XOR swizzle byte ^= (row&7)<<4) ----
        #pragma unroll
        for (int t = 0; t < 4; ++t)
            #pragma unroll
            for (int r = 0; r < 4; ++r) {
                float p = __expf(sc[t][r] - mrow[r]);
                lrow[r] += p;
                int row  = 4 * g + r;
                int boff = (row * 128 + (16 * t + c16) * 2) ^ ((row & 7) << 4);
                *(unsigned short*)((char*)pl + boff) = f2bf(p);
            }

        // ---- P A-fragments (row=c16, k=key=32c2+8g+e) ----
        short8 pa[2];
        #pragma unroll
        for (int c2 = 0; c2 < 2; ++c2) {
            int boff = (c16 * 128 + 64 * c2 + 16 * g) ^ ((c16 & 7) << 4);
            pa[c2] = *(const short8*)((const char*)pl + boff);
        }

        // ---- PV: ctx[q][dh] += P[q][key] * V[key][dh], V read from vT[dh][key] ----
        #pragma unroll
        for (int t2 = 0; t2 < 4; ++t2)
            #pragma unroll
            for (int c2 = 0; c2 < 2; ++c2)
                ctx[t2] = __builtin_amdgcn_mfma_f32_16x16x32_bf16(
                    pa[c2],
                    *(const short8*)&vp[(size_t)(16 * t2 + c16) * S_ + kv + 32 * c2 + 8 * g],
                    ctx[t2], 0, 0, 0);
    }

    // ---- final row-sum reduce + normalize + store ----
    #pragma unroll
    for (int r = 0; r < 4; ++r) {
        float v = lrow[r];
        v += __shfl_xor(v, 1);
        v += __shfl_xor(v, 2);
        v += __shfl_xor(v, 4);
        v += __shfl_xor(v, 8);
        lrow[r] = 1.0f / v;
    }
    #pragma unroll
    for (int t2 = 0; t2 < 4; ++t2)
        #pragma unroll
        for (int r = 0; r < 4; ++r)
            out[(size_t)(b * S_ + q0 + 4 * g + r) * D_ + h * DH + 16 * t2 + c16] =
                ctx[t2][r] * lrow[r];
}

extern "C" void kernel_launch(void* const* d_in, const int* in_sizes, int n_in,
                              void* d_out, int out_size, void* d_ws, size_t ws_size,
                              hipStream_t stream) {
    (void)in_sizes; (void)n_in; (void)out_size; (void)ws_size;
    const float* hid  = (const float*)d_in[0];
    const float* sp   = (const float*)d_in[1];
    const float* mask = (const float*)d_in[2];
    const float* Wq   = (const float*)d_in[3];
    const float* Wk   = (const float*)d_in[4];
    const float* Wv   = (const float*)d_in[5];
    float* out = (float*)d_out;

    unsigned short* qk_ws = (unsigned short*)d_ws;       // q (8MB) + k (8MB)
    unsigned short* vt_ws = qk_ws + 2 * (size_t)QKSZ;    // vT (8MB)

    qkv_proj<<<dim3(32 * 24), dim3(256), 0, stream>>>(hid, sp, Wq, Wk, Wv, qk_ws, vt_ws);
    attn_fwd<<<dim3(32 * 32), dim3(256), 0, stream>>>(qk_ws, vt_ws, mask, out);
}

// Round 3
// 386.798 us; speedup vs baseline: 2.0546x; 2.0546x over previous
//
#include <hip/hip_runtime.h>
#include <math.h>

#define B_  2
#define S_  2048
#define D_  1024
#define H_  16
#define DH  64
#define M_  (B_*S_)     // 4096
#define QKSZ 4194304    // B*H*S*DH

typedef __attribute__((ext_vector_type(4))) float  f32x4;
typedef __attribute__((ext_vector_type(8))) short  short8;
typedef __attribute__((ext_vector_type(8))) unsigned short ushort8;
typedef __attribute__((ext_vector_type(4))) unsigned short us4;

static __device__ __forceinline__ unsigned short f2bf(float x) {
    union { float f; unsigned int u; } v; v.f = x;
    unsigned int u = v.u;
    u += 0x7fffu + ((u >> 16) & 1u);   // round-to-nearest-even
    return (unsigned short)(u >> 16);
}

// ---------------------------------------------------------------------------
// Kernel 1: QKV projection as bf16 MFMA GEMM (fp32 inputs reg-staged -> bf16
// LDS tiles), fused RoPE epilogue. C[m,n] = sum_k hid[m,k]*W[n,k].
// Tile 128x128, BK=32, 4 waves (2x2), mfma_f32_16x16x32_bf16.
// Outputs: q,k bf16 [bh][s][dh]; v bf16 transposed [bh][dh][s].
// ---------------------------------------------------------------------------
__global__ __launch_bounds__(256) void qkv_proj(
    const float* __restrict__ hid,
    const float* __restrict__ sp,     // (S,64): [:,0:32]=sin, [:,32:64]=cos
    const float* __restrict__ Wq,
    const float* __restrict__ Wk,
    const float* __restrict__ Wv,
    unsigned short* __restrict__ qk_ws,
    unsigned short* __restrict__ vt_ws)
{
    __shared__ unsigned short As[128 * 32];   // 8 KB, [row][k] linear
    __shared__ unsigned short Bs[128 * 32];   // 8 KB

    const int tid    = threadIdx.x;
    const int tile_m = (blockIdx.x & 31) * 128;   // 32 m-tiles
    const int tile_n = (blockIdx.x >> 5) * 128;   // 24 n-tiles

    const float* W; int nloc;
    if (tile_n < 1024)      { W = Wq; nloc = tile_n; }
    else if (tile_n < 2048) { W = Wk; nloc = tile_n - 1024; }
    else                    { W = Wv; nloc = tile_n - 2048; }

    const int w    = tid >> 6, lane = tid & 63;
    const int wr   = w >> 1,  wc   = w & 1;       // wave -> 64x64 quadrant
    const int g    = lane >> 4, c16 = lane & 15;
    const int srow = tid >> 3;                    // staging: 0..31
    const int scol = (tid & 7) * 4;               // staging: 0,4,..,28

    f32x4 acc[4][4];
    #pragma unroll
    for (int i = 0; i < 4; ++i)
        #pragma unroll
        for (int j = 0; j < 4; ++j)
            acc[i][j][0] = acc[i][j][1] = acc[i][j][2] = acc[i][j][3] = 0.f;

    for (int k0 = 0; k0 < 1024; k0 += 32) {
        // ---- stage A,B tiles: fp32 global -> bf16 LDS (lane-linear, conflict-free)
        #pragma unroll
        for (int p = 0; p < 4; ++p) {
            const int row = p * 32 + srow;
            float4 a = *(const float4*)&hid[(size_t)(tile_m + row) * 1024 + k0 + scol];
            float4 b = *(const float4*)&W  [(size_t)(nloc   + row) * 1024 + k0 + scol];
            us4 ap, bp;
            ap[0] = f2bf(a.x); ap[1] = f2bf(a.y); ap[2] = f2bf(a.z); ap[3] = f2bf(a.w);
            bp[0] = f2bf(b.x); bp[1] = f2bf(b.y); bp[2] = f2bf(b.z); bp[3] = f2bf(b.w);
            *(us4*)&As[p * 1024 + tid * 4] = ap;
            *(us4*)&Bs[p * 1024 + tid * 4] = bp;
        }
        __syncthreads();

        // ---- fragments + 16 MFMAs
        short8 af[4], bf[4];
        #pragma unroll
        for (int i = 0; i < 4; ++i)
            af[i] = *(const short8*)&As[(wr * 64 + i * 16 + c16) * 32 + g * 8];
        #pragma unroll
        for (int j = 0; j < 4; ++j)
            bf[j] = *(const short8*)&Bs[(wc * 64 + j * 16 + c16) * 32 + g * 8];
        #pragma unroll
        for (int i = 0; i < 4; ++i)
            #pragma unroll
            for (int j = 0; j < 4; ++j)
                acc[i][j] = __builtin_amdgcn_mfma_f32_16x16x32_bf16(
                    af[i], bf[j], acc[i][j], 0, 0, 0);
        __syncthreads();
    }

    // ---- epilogue: C element [m = tile_m + wr*64 + i*16 + 4g + r]
    //                          [n = tile_n + wc*64 + j*16 + c16]
    if (tile_n < 2048) {
        // Q or K: apply RoPE, store bf16 [bh][s][dh]
        const int isK = (tile_n >= 1024) ? 1 : 0;
        unsigned short* qkb = qk_ws + (size_t)isK * QKSZ;
        const int head = ((tile_n - (isK ? 1024 : 0)) + wc * 64) >> 6;
        #pragma unroll
        for (int j = 0; j < 4; ++j) {
            const int dh = j * 16 + c16;
            const int p  = dh >> 1;
            const int odd = dh & 1;
            #pragma unroll
            for (int i = 0; i < 4; ++i) {
                #pragma unroll
                for (int r = 0; r < 4; ++r) {
                    const int m = tile_m + wr * 64 + i * 16 + 4 * g + r;
                    const int b = m >> 11, s = m & 2047;
                    float v    = acc[i][j][r];
                    float part = __shfl_xor(v, 1);
                    float sv = sp[s * 64 + p];
                    float cv = sp[s * 64 + 32 + p];
                    float o  = odd ? (v * cv + part * sv) : (v * cv - part * sv);
                    qkb[((size_t)(b * H_ + head) * S_ + s) * DH + dh] = f2bf(o);
                }
            }
        }
    } else {
        // V: store transposed bf16 [bh][dh][s]; rows 4g+r are 4 consecutive s
        const int head = (tile_n - 2048 + wc * 64) >> 6;
        #pragma unroll
        for (int j = 0; j < 4; ++j) {
            const int dh = j * 16 + c16;
            #pragma unroll
            for (int i = 0; i < 4; ++i) {
                const int m0 = tile_m + wr * 64 + i * 16 + 4 * g;
                const int b = m0 >> 11, s0 = m0 & 2047;
                us4 o;
                o[0] = f2bf(acc[i][j][0]); o[1] = f2bf(acc[i][j][1]);
                o[2] = f2bf(acc[i][j][2]); o[3] = f2bf(acc[i][j][3]);
                *(us4*)&vt_ws[((size_t)(b * H_ + head) * DH + dh) * S_ + s0] = o;
            }
        }
    }
}

// ---------------------------------------------------------------------------
// Kernel 2: flash attention, bf16 MFMA 16x16x32, fp32 accum. (unchanged)
// Block = 4 waves; wave w owns 16 q-rows; KV tile = 64.
// ---------------------------------------------------------------------------
__global__ __launch_bounds__(256) void attn_fwd(
    const unsigned short* __restrict__ qk_ws,
    const unsigned short* __restrict__ vt_ws,
    const float* __restrict__ maskp,   // (B, S)
    float* __restrict__ out)           // (B, S, D)
{
    __shared__ unsigned short Pl[4][16 * 64];   // per-wave P buffer (XOR-swizzled)

    const int tid  = threadIdx.x;
    const int w    = tid >> 6, lane = tid & 63;
    const int g    = lane >> 4, c16 = lane & 15;
    const int qt   = blockIdx.x & 31;
    const int bh   = blockIdx.x >> 5;          // 0..31
    const int b    = bh >> 4, h = bh & 15;

    const unsigned short* qp = qk_ws + (size_t)bh * (S_ * DH);
    const unsigned short* kp = qk_ws + QKSZ + (size_t)bh * (S_ * DH);
    const unsigned short* vp = vt_ws + (size_t)bh * (DH * S_);
    const float* mp = maskp + b * S_;
    const int q0 = qt * 64 + w * 16;

    short8 qf[2];
    #pragma unroll
    for (int c = 0; c < 2; ++c)
        qf[c] = *(const short8*)&qp[(size_t)(q0 + c16) * DH + 32 * c + 8 * g];

    f32x4 ctx[4];
    float mrow[4], lrow[4];
    #pragma unroll
    for (int t = 0; t < 4; ++t) { ctx[t][0] = ctx[t][1] = ctx[t][2] = ctx[t][3] = 0.f; }
    #pragma unroll
    for (int r = 0; r < 4; ++r) { mrow[r] = -1e30f; lrow[r] = 0.f; }

    unsigned short* pl = &Pl[w][0];

    for (int kv = 0; kv < S_; kv += 64) {
        f32x4 sa[4];
        #pragma unroll
        for (int t = 0; t < 4; ++t) { sa[t][0] = sa[t][1] = sa[t][2] = sa[t][3] = 0.f; }
        #pragma unroll
        for (int t = 0; t < 4; ++t)
            #pragma unroll
            for (int c = 0; c < 2; ++c)
                sa[t] = __builtin_amdgcn_mfma_f32_16x16x32_bf16(
                    qf[c],
                    *(const short8*)&kp[(size_t)(kv + 16 * t + c16) * DH + 32 * c + 8 * g],
                    sa[t], 0, 0, 0);

        float sc[4][4];
        #pragma unroll
        for (int t = 0; t < 4; ++t) {
            float mv = mp[kv + 16 * t + c16];
            #pragma unroll
            for (int r = 0; r < 4; ++r) sc[t][r] = sa[t][r] * 0.125f + mv;
        }

        float fac[4];
        #pragma unroll
        for (int r = 0; r < 4; ++r) {
            float v = fmaxf(fmaxf(sc[0][r], sc[1][r]), fmaxf(sc[2][r], sc[3][r]));
            v = fmaxf(v, __shfl_xor(v, 1));
            v = fmaxf(v, __shfl_xor(v, 2));
            v = fmaxf(v, __shfl_xor(v, 4));
            v = fmaxf(v, __shfl_xor(v, 8));
            float nm = fmaxf(mrow[r], v);
            fac[r] = __expf(mrow[r] - nm);
            mrow[r] = nm;
            lrow[r] *= fac[r];
        }
        #pragma unroll
        for (int t = 0; t < 4; ++t)
            #pragma unroll
            for (int r = 0; r < 4; ++r) ctx[t][r] *= fac[r];

        #pragma unroll
        for (int t = 0; t < 4; ++t)
            #pragma unroll
            for (int r = 0; r < 4; ++r) {
                float p = __expf(sc[t][r] - mrow[r]);
                lrow[r] += p;
                int row  = 4 * g + r;
                int boff = (row * 128 + (16 * t + c16) * 2) ^ ((row & 7) << 4);
                *(unsigned short*)((char*)pl + boff) = f2bf(p);
            }

        short8 pa[2];
        #pragma unroll
        for (int c2 = 0; c2 < 2; ++c2) {
            int boff = (c16 * 128 + 64 * c2 + 16 * g) ^ ((c16 & 7) << 4);
            pa[c2] = *(const short8*)((const char*)pl + boff);
        }

        #pragma unroll
        for (int t2 = 0; t2 < 4; ++t2)
            #pragma unroll
            for (int c2 = 0; c2 < 2; ++c2)
                ctx[t2] = __builtin_amdgcn_mfma_f32_16x16x32_bf16(
                    pa[c2],
                    *(const short8*)&vp[(size_t)(16 * t2 + c16) * S_ + kv + 32 * c2 + 8 * g],
                    ctx[t2], 0, 0, 0);
    }

    #pragma unroll
    for (int r = 0; r < 4; ++r) {
        float v = lrow[r];
        v += __shfl_xor(v, 1);
        v += __shfl_xor(v, 2);
        v += __shfl_xor(v, 4);
        v += __shfl_xor(v, 8);
        lrow[r] = 1.0f / v;
    }
    #pragma unroll
    for (int t2 = 0; t2 < 4; ++t2)
        #pragma unroll
        for (int r = 0; r < 4; ++r)
            out[(size_t)(b * S_ + q0 + 4 * g + r) * D_ + h * DH + 16 * t2 + c16] =
                ctx[t2][r] * lrow[r];
}

extern "C" void kernel_launch(void* const* d_in, const int* in_sizes, int n_in,
                              void* d_out, int out_size, void* d_ws, size_t ws_size,
                              hipStream_t stream) {
    (void)in_sizes; (void)n_in; (void)out_size; (void)ws_size;
    const float* hid  = (const float*)d_in[0];
    const float* sp   = (const float*)d_in[1];
    const float* mask = (const float*)d_in[2];
    const float* Wq   = (const float*)d_in[3];
    const float* Wk   = (const float*)d_in[4];
    const float* Wv   = (const float*)d_in[5];
    float* out = (float*)d_out;

    unsigned short* qk_ws = (unsigned short*)d_ws;       // q (8MB) + k (8MB)
    unsigned short* vt_ws = qk_ws + 2 * (size_t)QKSZ;    // vT (8MB)

    qkv_proj<<<dim3(32 * 24), dim3(256), 0, stream>>>(hid, sp, Wq, Wk, Wv, qk_ws, vt_ws);
    attn_fwd<<<dim3(32 * 32), dim3(256), 0, stream>>>(qk_ws, vt_ws, mask, out);
}

// Round 6
// 228.964 us; speedup vs baseline: 3.4710x; 1.6893x over previous
//
#include <hip/hip_runtime.h>
#include <math.h>

#define B_  2
#define S_  2048
#define D_  1024
#define H_  16
#define DH  64
#define M_  (B_*S_)     // 4096
#define QKSZ 4194304    // B*H*S*DH

typedef __attribute__((ext_vector_type(4)))  float  f32x4;
typedef __attribute__((ext_vector_type(16))) float  f32x16;
typedef __attribute__((ext_vector_type(8)))  short  short8;
typedef __attribute__((ext_vector_type(8)))  unsigned short ushort8;
typedef __attribute__((ext_vector_type(4)))  unsigned short us4;

static __device__ __forceinline__ unsigned short f2bf(float x) {
    union { float f; unsigned int u; } v; v.f = x;
    unsigned int u = v.u;
    u += 0x7fffu + ((u >> 16) & 1u);   // round-to-nearest-even
    return (unsigned short)(u >> 16);
}

// ---------------------------------------------------------------------------
// Kernel 1: QKV projection as bf16 MFMA GEMM (unchanged from round 3)
// ---------------------------------------------------------------------------
__global__ __launch_bounds__(256) void qkv_proj(
    const float* __restrict__ hid,
    const float* __restrict__ sp,     // (S,64): [:,0:32]=sin, [:,32:64]=cos
    const float* __restrict__ Wq,
    const float* __restrict__ Wk,
    const float* __restrict__ Wv,
    unsigned short* __restrict__ qk_ws,
    unsigned short* __restrict__ vt_ws)
{
    __shared__ unsigned short As[128 * 32];
    __shared__ unsigned short Bs[128 * 32];

    const int tid    = threadIdx.x;
    const int tile_m = (blockIdx.x & 31) * 128;
    const int tile_n = (blockIdx.x >> 5) * 128;

    const float* W; int nloc;
    if (tile_n < 1024)      { W = Wq; nloc = tile_n; }
    else if (tile_n < 2048) { W = Wk; nloc = tile_n - 1024; }
    else                    { W = Wv; nloc = tile_n - 2048; }

    const int w    = tid >> 6, lane = tid & 63;
    const int wr   = w >> 1,  wc   = w & 1;
    const int g    = lane >> 4, c16 = lane & 15;
    const int srow = tid >> 3;
    const int scol = (tid & 7) * 4;

    f32x4 acc[4][4];
    #pragma unroll
    for (int i = 0; i < 4; ++i)
        #pragma unroll
        for (int j = 0; j < 4; ++j)
            acc[i][j][0] = acc[i][j][1] = acc[i][j][2] = acc[i][j][3] = 0.f;

    for (int k0 = 0; k0 < 1024; k0 += 32) {
        #pragma unroll
        for (int p = 0; p < 4; ++p) {
            const int row = p * 32 + srow;
            float4 a = *(const float4*)&hid[(size_t)(tile_m + row) * 1024 + k0 + scol];
            float4 b = *(const float4*)&W  [(size_t)(nloc   + row) * 1024 + k0 + scol];
            us4 ap, bp;
            ap[0] = f2bf(a.x); ap[1] = f2bf(a.y); ap[2] = f2bf(a.z); ap[3] = f2bf(a.w);
            bp[0] = f2bf(b.x); bp[1] = f2bf(b.y); bp[2] = f2bf(b.z); bp[3] = f2bf(b.w);
            *(us4*)&As[p * 1024 + tid * 4] = ap;
            *(us4*)&Bs[p * 1024 + tid * 4] = bp;
        }
        __syncthreads();

        short8 af[4], bf[4];
        #pragma unroll
        for (int i = 0; i < 4; ++i)
            af[i] = *(const short8*)&As[(wr * 64 + i * 16 + c16) * 32 + g * 8];
        #pragma unroll
        for (int j = 0; j < 4; ++j)
            bf[j] = *(const short8*)&Bs[(wc * 64 + j * 16 + c16) * 32 + g * 8];
        #pragma unroll
        for (int i = 0; i < 4; ++i)
            #pragma unroll
            for (int j = 0; j < 4; ++j)
                acc[i][j] = __builtin_amdgcn_mfma_f32_16x16x32_bf16(
                    af[i], bf[j], acc[i][j], 0, 0, 0);
        __syncthreads();
    }

    if (tile_n < 2048) {
        const int isK = (tile_n >= 1024) ? 1 : 0;
        unsigned short* qkb = qk_ws + (size_t)isK * QKSZ;
        const int head = ((tile_n - (isK ? 1024 : 0)) + wc * 64) >> 6;
        #pragma unroll
        for (int j = 0; j < 4; ++j) {
            const int dh = j * 16 + c16;
            const int p  = dh >> 1;
            const int odd = dh & 1;
            #pragma unroll
            for (int i = 0; i < 4; ++i) {
                #pragma unroll
                for (int r = 0; r < 4; ++r) {
                    const int m = tile_m + wr * 64 + i * 16 + 4 * g + r;
                    const int b = m >> 11, s = m & 2047;
                    float v    = acc[i][j][r];
                    float part = __shfl_xor(v, 1);
                    float sv = sp[s * 64 + p];
                    float cv = sp[s * 64 + 32 + p];
                    float o  = odd ? (v * cv + part * sv) : (v * cv - part * sv);
                    qkb[((size_t)(b * H_ + head) * S_ + s) * DH + dh] = f2bf(o);
                }
            }
        }
    } else {
        const int head = (tile_n - 2048 + wc * 64) >> 6;
        #pragma unroll
        for (int j = 0; j < 4; ++j) {
            const int dh = j * 16 + c16;
            #pragma unroll
            for (int i = 0; i < 4; ++i) {
                const int m0 = tile_m + wr * 64 + i * 16 + 4 * g;
                const int b = m0 >> 11, s0 = m0 & 2047;
                us4 o;
                o[0] = f2bf(acc[i][j][0]); o[1] = f2bf(acc[i][j][1]);
                o[2] = f2bf(acc[i][j][2]); o[3] = f2bf(acc[i][j][3]);
                *(us4*)&vt_ws[((size_t)(b * H_ + head) * DH + dh) * S_ + s0] = o;
            }
        }
    }
}

// ---------------------------------------------------------------------------
// Kernel 2: flash attention, swapped-QK^T 32x32 MFMA, in-register softmax.
// Block = 4 waves x 32 q-rows = 128 q. KV step = 64, double-buffered LDS
// (K [64kv][64dh], V^T [64dh][64kv], both XOR-swizzled byte^=(row&7)<<4).
// S^T layout per lane: q = lane&31, key(reg) = (reg&3)+8*(reg>>2)+4*hi.
// Cross-half exchanges via __shfl_xor(.,32) (direction-agnostic; permlane
// A/B deferred until a passing baseline exists).
// ---------------------------------------------------------------------------
__global__ __launch_bounds__(256, 2) void attn_fwd(
    const unsigned short* __restrict__ qk_ws,
    const unsigned short* __restrict__ vt_ws,
    const float* __restrict__ maskp,   // (B, S)
    float* __restrict__ out)           // (B, S, D)
{
    __shared__ unsigned short K_lds[2][64 * 64];
    __shared__ unsigned short V_lds[2][64 * 64];

    const int tid  = threadIdx.x;
    const int w    = tid >> 6, lane = tid & 63;
    const int hi   = lane >> 5, c32 = lane & 31;
    const int qt   = blockIdx.x & 15;          // 16 q-tiles of 128
    const int bh   = blockIdx.x >> 4;          // 0..31
    const int b    = bh >> 4, h = bh & 15;

    const unsigned short* qp = qk_ws + (size_t)bh * (S_ * DH);
    const unsigned short* kp = qk_ws + QKSZ + (size_t)bh * (S_ * DH);
    const unsigned short* vp = vt_ws + (size_t)bh * (DH * S_);
    const float* mp = maskp + b * S_;

    const int q = qt * 128 + w * 32 + c32;     // this lane's q-row

    // Q fragments (B-operand): col=c32=q, k(dh) = ks*16 + 8*hi + e
    short8 qf[4];
    #pragma unroll
    for (int ks = 0; ks < 4; ++ks)
        qf[ks] = *(const short8*)&qp[(size_t)q * DH + ks * 16 + 8 * hi];

    f32x16 ctx[2];
    #pragma unroll
    for (int d = 0; d < 2; ++d)
        #pragma unroll
        for (int r = 0; r < 16; ++r) ctx[d][r] = 0.f;
    float mrow = -1e30f, lsum = 0.f;

    // ---- staging helpers (each thread: 2 x 16B for K, 2 x 16B for V) ----
    ushort8 rk[2], rv[2];
    const int su0 = tid, su1 = tid + 256;

    auto LOADT = [&](int t) {
        const int kv = t * 64;
        {
            int row = su0 >> 3, c = (su0 & 7) * 8;
            rk[0] = *(const ushort8*)&kp[(size_t)(kv + row) * DH + c];
            rv[0] = *(const ushort8*)&vp[(size_t)row * S_ + kv + c];
        }
        {
            int row = su1 >> 3, c = (su1 & 7) * 8;
            rk[1] = *(const ushort8*)&kp[(size_t)(kv + row) * DH + c];
            rv[1] = *(const ushort8*)&vp[(size_t)row * S_ + kv + c];
        }
    };
    auto WRITET = [&](int buf) {
        {
            int row = su0 >> 3, c = (su0 & 7) * 16;
            int off = (row * 128 + c) ^ ((row & 7) << 4);
            *(ushort8*)((char*)&K_lds[buf][0] + off) = rk[0];
            *(ushort8*)((char*)&V_lds[buf][0] + off) = rv[0];
        }
        {
            int row = su1 >> 3, c = (su1 & 7) * 16;
            int off = (row * 128 + c) ^ ((row & 7) << 4);
            *(ushort8*)((char*)&K_lds[buf][0] + off) = rk[1];
            *(ushort8*)((char*)&V_lds[buf][0] + off) = rv[1];
        }
    };

    LOADT(0); WRITET(0); LOADT(1);
    __syncthreads();

    const int NT = S_ / 64;   // 32
    for (int t = 0; t < NT; ++t) {
        const int cur = t & 1;
        const int kv  = t * 64;
        const char* Kb = (const char*)&K_lds[cur][0];
        const char* Vb = (const char*)&V_lds[cur][0];

        // ---- QK^T swapped: S^T[key][q], 2 key-tiles of 32 ----
        f32x16 sa0, sa1;
        #pragma unroll
        for (int r = 0; r < 16; ++r) { sa0[r] = 0.f; sa1[r] = 0.f; }
        #pragma unroll
        for (int ks = 0; ks < 4; ++ks) {
            const int colb = ks * 32 + hi * 16;
            short8 kf0 = *(const short8*)(Kb + ((c32 * 128 + colb) ^ ((c32 & 7) << 4)));
            short8 kf1 = *(const short8*)(Kb + (((32 + c32) * 128 + colb) ^ ((c32 & 7) << 4)));
            sa0 = __builtin_amdgcn_mfma_f32_32x32x16_bf16(kf0, qf[ks], sa0, 0, 0, 0);
            sa1 = __builtin_amdgcn_mfma_f32_32x32x16_bf16(kf1, qf[ks], sa1, 0, 0, 0);
        }

        // ---- scale + mask ----
        float sc0[16], sc1[16];
        #pragma unroll
        for (int r = 0; r < 16; ++r) {
            const int koff = (r & 3) + 8 * (r >> 2) + 4 * hi;
            sc0[r] = sa0[r] * 0.125f + mp[kv + koff];
            sc1[r] = sa1[r] * 0.125f + mp[kv + 32 + koff];
        }

        // ---- in-lane max over this lane's 32 keys, then cross-half combine ----
        float pm = sc0[0];
        #pragma unroll
        for (int r = 1; r < 16; ++r) pm = fmaxf(pm, sc0[r]);
        #pragma unroll
        for (int r = 0; r < 16; ++r) pm = fmaxf(pm, sc1[r]);
        pm = fmaxf(pm, __shfl_xor(pm, 32));

        const float mnew = fmaxf(mrow, pm);
        const float fac  = __expf(mrow - mnew);
        mrow = mnew;
        lsum *= fac;
        #pragma unroll
        for (int d = 0; d < 2; ++d)
            #pragma unroll
            for (int r = 0; r < 16; ++r) ctx[d][r] *= fac;

        // ---- P = exp(sc - m), per-lane partial sum ----
        float p0[16], p1[16];
        float ps = 0.f;
        #pragma unroll
        for (int r = 0; r < 16; ++r) { p0[r] = __expf(sc0[r] - mnew); ps += p0[r]; }
        #pragma unroll
        for (int r = 0; r < 16; ++r) { p1[r] = __expf(sc1[r] - mnew); ps += p1[r]; }
        lsum += ps;

        // ---- pack P -> PV B-fragments: f2bf pairs + cross-half shfl_xor(32) ----
        // lane(hi,q) needs keys ks4*16 + 8*hi + e; own regs hold keys
        // crow(r,hi)=(r&3)+8*(r>>2)+4*hi  -> exchange word pairs (r, r+4).
        short8 pf[4];
        #pragma unroll
        for (int ks4 = 0; ks4 < 4; ++ks4) {
            const float* pp = (ks4 < 2) ? p0 : p1;
            const int k8 = (ks4 & 1) * 8;
            unsigned int a0 = ((unsigned int)f2bf(pp[k8 + 1]) << 16) | f2bf(pp[k8 + 0]);
            unsigned int a1 = ((unsigned int)f2bf(pp[k8 + 3]) << 16) | f2bf(pp[k8 + 2]);
            unsigned int b0 = ((unsigned int)f2bf(pp[k8 + 5]) << 16) | f2bf(pp[k8 + 4]);
            unsigned int b1 = ((unsigned int)f2bf(pp[k8 + 7]) << 16) | f2bf(pp[k8 + 6]);
            unsigned int ax0 = (unsigned int)__shfl_xor((int)a0, 32);
            unsigned int ax1 = (unsigned int)__shfl_xor((int)a1, 32);
            unsigned int bx0 = (unsigned int)__shfl_xor((int)b0, 32);
            unsigned int bx1 = (unsigned int)__shfl_xor((int)b1, 32);
            union { unsigned int u[4]; short8 v; } fr;
            fr.u[0] = hi ? bx0 : a0;    // keys +0,1  (hi=1: partner's 8,9)
            fr.u[1] = hi ? bx1 : a1;    // keys +2,3
            fr.u[2] = hi ? b0  : ax0;   // keys +4,5  (hi=1: own 12,13)
            fr.u[3] = hi ? b1  : ax1;   // keys +6,7
            pf[ks4] = fr.v;
        }

        // ---- prefetch/stage next tile between QK and PV ----
        if (t + 1 < NT) {
            __syncthreads();              // everyone done reading buf[cur^1]
            WRITET(cur ^ 1);              // write tile t+1
            if (t + 2 < NT) LOADT(t + 2); // issue loads for t+2
        }

        // ---- PV: ctx[dh][q] += V^T[dh][key] * P^T[key][q] ----
        #pragma unroll
        for (int ks4 = 0; ks4 < 4; ++ks4) {
            const int colb = ks4 * 32 + hi * 16;
            short8 vf0 = *(const short8*)(Vb + ((c32 * 128 + colb) ^ ((c32 & 7) << 4)));
            short8 vf1 = *(const short8*)(Vb + (((32 + c32) * 128 + colb) ^ ((c32 & 7) << 4)));
            ctx[0] = __builtin_amdgcn_mfma_f32_32x32x16_bf16(vf0, pf[ks4], ctx[0], 0, 0, 0);
            ctx[1] = __builtin_amdgcn_mfma_f32_32x32x16_bf16(vf1, pf[ks4], ctx[1], 0, 0, 0);
        }

        if (t + 1 < NT) __syncthreads();  // writes of tile t+1 visible
    }

    // ---- final: lsum across halves, normalize, store ----
    const float inv = 1.0f / (lsum + __shfl_xor(lsum, 32));

    float* ob = out + ((size_t)(b * S_ + q) * D_) + h * DH;
    #pragma unroll
    for (int d = 0; d < 2; ++d)
        #pragma unroll
        for (int q4 = 0; q4 < 4; ++q4) {
            f32x4 st;
            st[0] = ctx[d][q4 * 4 + 0] * inv;
            st[1] = ctx[d][q4 * 4 + 1] * inv;
            st[2] = ctx[d][q4 * 4 + 2] * inv;
            st[3] = ctx[d][q4 * 4 + 3] * inv;
            *(f32x4*)&ob[d * 32 + 8 * q4 + 4 * hi] = st;
        }
}

extern "C" void kernel_launch(void* const* d_in, const int* in_sizes, int n_in,
                              void* d_out, int out_size, void* d_ws, size_t ws_size,
                              hipStream_t stream) {
    (void)in_sizes; (void)n_in; (void)out_size; (void)ws_size;
    const float* hid  = (const float*)d_in[0];
    const float* sp   = (const float*)d_in[1];
    const float* mask = (const float*)d_in[2];
    const float* Wq   = (const float*)d_in[3];
    const float* Wk   = (const float*)d_in[4];
    const float* Wv   = (const float*)d_in[5];
    float* out = (float*)d_out;

    unsigned short* qk_ws = (unsigned short*)d_ws;       // q (8MB) + k (8MB)
    unsigned short* vt_ws = qk_ws + 2 * (size_t)QKSZ;    // vT (8MB)

    qkv_proj<<<dim3(32 * 24), dim3(256), 0, stream>>>(hid, sp, Wq, Wk, Wv, qk_ws, vt_ws);
    attn_fwd<<<dim3(32 * 16), dim3(256), 0, stream>>>(qk_ws, vt_ws, mask, out);
}

// Round 7
// 197.196 us; speedup vs baseline: 4.0301x; 1.1611x over previous
//
#include <hip/hip_runtime.h>
#include <math.h>

#define B_  2
#define S_  2048
#define D_  1024
#define H_  16
#define DH  64
#define M_  (B_*S_)     // 4096
#define QKSZ 4194304    // B*H*S*DH

typedef __attribute__((ext_vector_type(4)))  float  f32x4;
typedef __attribute__((ext_vector_type(16))) float  f32x16;
typedef __attribute__((ext_vector_type(8)))  short  short8;
typedef __attribute__((ext_vector_type(8)))  unsigned short ushort8;
typedef __attribute__((ext_vector_type(4)))  unsigned short us4;

static __device__ __forceinline__ unsigned short f2bf(float x) {
    union { float f; unsigned int u; } v; v.f = x;
    unsigned int u = v.u;
    u += 0x7fffu + ((u >> 16) & 1u);   // round-to-nearest-even
    return (unsigned short)(u >> 16);
}

typedef __attribute__((address_space(3))) void       lds_void;
typedef const __attribute__((address_space(1))) void gbl_void;

static __device__ __forceinline__ void gload_lds16(const unsigned short* g,
                                                   unsigned short* l) {
    __builtin_amdgcn_global_load_lds((gbl_void*)g, (lds_void*)l, 16, 0, 0);
}

// ---------------------------------------------------------------------------
// Kernel 0: fp32 -> bf16 pre-convert (hid 4M elems, then Wq|Wk|Wv 3M elems)
// ---------------------------------------------------------------------------
__global__ __launch_bounds__(256) void cvt_all(
    const float* __restrict__ hid, const float* __restrict__ Wq,
    const float* __restrict__ Wk,  const float* __restrict__ Wv,
    unsigned short* __restrict__ hb, unsigned short* __restrict__ wb)
{
    const size_t i = ((size_t)blockIdx.x * 256 + threadIdx.x) * 8;
    const float* s; unsigned short* d;
    if (i < 4194304) { s = hid + i; d = hb + i; }
    else {
        size_t j = i - 4194304;
        const float* w = (j < 1048576) ? Wq : (j < 2097152) ? Wk : Wv;
        s = w + (j & 1048575);
        d = wb + j;
    }
    float4 a = *(const float4*)s, b = *(const float4*)(s + 4);
    ushort8 o;
    o[0] = f2bf(a.x); o[1] = f2bf(a.y); o[2] = f2bf(a.z); o[3] = f2bf(a.w);
    o[4] = f2bf(b.x); o[5] = f2bf(b.y); o[6] = f2bf(b.z); o[7] = f2bf(b.w);
    *(ushort8*)d = o;
}

// ---------------------------------------------------------------------------
// Kernel 1 (fast): QKV GEMM, m97 structure: global_load_lds(16B) staging,
// 128x128 tile, BK=32, 4 waves (2x2), 16 MFMA/wave/K-step. Fused RoPE.
// ---------------------------------------------------------------------------
__global__ __launch_bounds__(256) void qkv_gemm(
    const unsigned short* __restrict__ hb,   // bf16 [4096][1024]
    const unsigned short* __restrict__ wb,   // bf16 [3072][1024] (Wq|Wk|Wv)
    const float* __restrict__ sp,            // (S,64): sin | cos
    unsigned short* __restrict__ qk_ws,
    unsigned short* __restrict__ vt_ws)
{
    __shared__ unsigned short As[128 * 32];   // linear (global_load_lds dest)
    __shared__ unsigned short Bs[128 * 32];

    const int tid    = threadIdx.x;
    const int tile_m = (blockIdx.x & 31) * 128;
    const int tile_n = (blockIdx.x >> 5) * 128;

    const int w  = tid >> 6, lane = tid & 63;
    const int wr = w >> 1,  wc = w & 1;
    const int g  = lane >> 4, c16 = lane & 15;
    const int lr = lane >> 2;          // 0..15 row within 16-row chunk
    const int lc = (lane & 3) * 8;     // elem col 0,8,16,24

    // per-lane global row bases; per-wave uniform LDS chunk bases
    const size_t arow = (size_t)(tile_m + w * 16 + lr) * 1024 + lc;
    const size_t brow = (size_t)(tile_n + w * 16 + lr) * 1024 + lc;
    unsigned short* lA0 = &As[(w * 16) * 32];
    unsigned short* lA1 = &As[(w * 16 + 64) * 32];
    unsigned short* lB0 = &Bs[(w * 16) * 32];
    unsigned short* lB1 = &Bs[(w * 16 + 64) * 32];

    f32x4 acc[4][4];
    #pragma unroll
    for (int i = 0; i < 4; ++i)
        #pragma unroll
        for (int j = 0; j < 4; ++j)
            acc[i][j][0] = acc[i][j][1] = acc[i][j][2] = acc[i][j][3] = 0.f;

    for (int k0 = 0; k0 < 1024; k0 += 32) {
        gload_lds16(hb + arow + k0,             lA0);
        gload_lds16(hb + arow + 64 * 1024 + k0, lA1);
        gload_lds16(wb + brow + k0,             lB0);
        gload_lds16(wb + brow + 64 * 1024 + k0, lB1);
        __syncthreads();   // compiler drains vmcnt before barrier

        short8 af[4], bf[4];
        #pragma unroll
        for (int i = 0; i < 4; ++i)
            af[i] = *(const short8*)&As[(wr * 64 + i * 16 + c16) * 32 + g * 8];
        #pragma unroll
        for (int j = 0; j < 4; ++j)
            bf[j] = *(const short8*)&Bs[(wc * 64 + j * 16 + c16) * 32 + g * 8];
        __builtin_amdgcn_s_setprio(1);
        #pragma unroll
        for (int i = 0; i < 4; ++i)
            #pragma unroll
            for (int j = 0; j < 4; ++j)
                acc[i][j] = __builtin_amdgcn_mfma_f32_16x16x32_bf16(
                    af[i], bf[j], acc[i][j], 0, 0, 0);
        __builtin_amdgcn_s_setprio(0);
        __syncthreads();
    }

    // ---- epilogue: m = tile_m + wr*64 + i*16 + 4g + r ; n = tile_n + wc*64 + j*16 + c16
    if (tile_n < 2048) {
        const int isK = (tile_n >= 1024) ? 1 : 0;
        unsigned short* qkb = qk_ws + (size_t)isK * QKSZ;
        const int head = ((tile_n - (isK ? 1024 : 0)) + wc * 64) >> 6;
        #pragma unroll
        for (int j = 0; j < 4; ++j) {
            const int dh = j * 16 + c16;
            const int p  = dh >> 1;
            const int odd = dh & 1;
            #pragma unroll
            for (int i = 0; i < 4; ++i) {
                #pragma unroll
                for (int r = 0; r < 4; ++r) {
                    const int m = tile_m + wr * 64 + i * 16 + 4 * g + r;
                    const int b = m >> 11, s = m & 2047;
                    float v    = acc[i][j][r];
                    float part = __shfl_xor(v, 1);
                    float sv = sp[s * 64 + p];
                    float cv = sp[s * 64 + 32 + p];
                    float o  = odd ? (v * cv + part * sv) : (v * cv - part * sv);
                    qkb[((size_t)(b * H_ + head) * S_ + s) * DH + dh] = f2bf(o);
                }
            }
        }
    } else {
        const int head = (tile_n - 2048 + wc * 64) >> 6;
        #pragma unroll
        for (int j = 0; j < 4; ++j) {
            const int dh = j * 16 + c16;
            #pragma unroll
            for (int i = 0; i < 4; ++i) {
                const int m0 = tile_m + wr * 64 + i * 16 + 4 * g;
                const int b = m0 >> 11, s0 = m0 & 2047;
                us4 o;
                o[0] = f2bf(acc[i][j][0]); o[1] = f2bf(acc[i][j][1]);
                o[2] = f2bf(acc[i][j][2]); o[3] = f2bf(acc[i][j][3]);
                *(us4*)&vt_ws[((size_t)(b * H_ + head) * DH + dh) * S_ + s0] = o;
            }
        }
    }
}

// ---------------------------------------------------------------------------
// Kernel 1 (fallback, ws-tight): round-6 reg-staged qkv projection
// ---------------------------------------------------------------------------
__global__ __launch_bounds__(256) void qkv_proj(
    const float* __restrict__ hid,
    const float* __restrict__ sp,
    const float* __restrict__ Wq,
    const float* __restrict__ Wk,
    const float* __restrict__ Wv,
    unsigned short* __restrict__ qk_ws,
    unsigned short* __restrict__ vt_ws)
{
    __shared__ unsigned short As[128 * 32];
    __shared__ unsigned short Bs[128 * 32];

    const int tid    = threadIdx.x;
    const int tile_m = (blockIdx.x & 31) * 128;
    const int tile_n = (blockIdx.x >> 5) * 128;

    const float* W; int nloc;
    if (tile_n < 1024)      { W = Wq; nloc = tile_n; }
    else if (tile_n < 2048) { W = Wk; nloc = tile_n - 1024; }
    else                    { W = Wv; nloc = tile_n - 2048; }

    const int w    = tid >> 6, lane = tid & 63;
    const int wr   = w >> 1,  wc   = w & 1;
    const int g    = lane >> 4, c16 = lane & 15;
    const int srow = tid >> 3;
    const int scol = (tid & 7) * 4;

    f32x4 acc[4][4];
    #pragma unroll
    for (int i = 0; i < 4; ++i)
        #pragma unroll
        for (int j = 0; j < 4; ++j)
            acc[i][j][0] = acc[i][j][1] = acc[i][j][2] = acc[i][j][3] = 0.f;

    for (int k0 = 0; k0 < 1024; k0 += 32) {
        #pragma unroll
        for (int p = 0; p < 4; ++p) {
            const int row = p * 32 + srow;
            float4 a = *(const float4*)&hid[(size_t)(tile_m + row) * 1024 + k0 + scol];
            float4 b = *(const float4*)&W  [(size_t)(nloc   + row) * 1024 + k0 + scol];
            us4 ap, bp;
            ap[0] = f2bf(a.x); ap[1] = f2bf(a.y); ap[2] = f2bf(a.z); ap[3] = f2bf(a.w);
            bp[0] = f2bf(b.x); bp[1] = f2bf(b.y); bp[2] = f2bf(b.z); bp[3] = f2bf(b.w);
            *(us4*)&As[p * 1024 + tid * 4] = ap;
            *(us4*)&Bs[p * 1024 + tid * 4] = bp;
        }
        __syncthreads();

        short8 af[4], bf[4];
        #pragma unroll
        for (int i = 0; i < 4; ++i)
            af[i] = *(const short8*)&As[(wr * 64 + i * 16 + c16) * 32 + g * 8];
        #pragma unroll
        for (int j = 0; j < 4; ++j)
            bf[j] = *(const short8*)&Bs[(wc * 64 + j * 16 + c16) * 32 + g * 8];
        #pragma unroll
        for (int i = 0; i < 4; ++i)
            #pragma unroll
            for (int j = 0; j < 4; ++j)
                acc[i][j] = __builtin_amdgcn_mfma_f32_16x16x32_bf16(
                    af[i], bf[j], acc[i][j], 0, 0, 0);
        __syncthreads();
    }

    if (tile_n < 2048) {
        const int isK = (tile_n >= 1024) ? 1 : 0;
        unsigned short* qkb = qk_ws + (size_t)isK * QKSZ;
        const int head = ((tile_n - (isK ? 1024 : 0)) + wc * 64) >> 6;
        #pragma unroll
        for (int j = 0; j < 4; ++j) {
            const int dh = j * 16 + c16;
            const int p  = dh >> 1;
            const int odd = dh & 1;
            #pragma unroll
            for (int i = 0; i < 4; ++i) {
                #pragma unroll
                for (int r = 0; r < 4; ++r) {
                    const int m = tile_m + wr * 64 + i * 16 + 4 * g + r;
                    const int b = m >> 11, s = m & 2047;
                    float v    = acc[i][j][r];
                    float part = __shfl_xor(v, 1);
                    float sv = sp[s * 64 + p];
                    float cv = sp[s * 64 + 32 + p];
                    float o  = odd ? (v * cv + part * sv) : (v * cv - part * sv);
                    qkb[((size_t)(b * H_ + head) * S_ + s) * DH + dh] = f2bf(o);
                }
            }
        }
    } else {
        const int head = (tile_n - 2048 + wc * 64) >> 6;
        #pragma unroll
        for (int j = 0; j < 4; ++j) {
            const int dh = j * 16 + c16;
            #pragma unroll
            for (int i = 0; i < 4; ++i) {
                const int m0 = tile_m + wr * 64 + i * 16 + 4 * g;
                const int b = m0 >> 11, s0 = m0 & 2047;
                us4 o;
                o[0] = f2bf(acc[i][j][0]); o[1] = f2bf(acc[i][j][1]);
                o[2] = f2bf(acc[i][j][2]); o[3] = f2bf(acc[i][j][3]);
                *(us4*)&vt_ws[((size_t)(b * H_ + head) * DH + dh) * S_ + s0] = o;
            }
        }
    }
}

// ---------------------------------------------------------------------------
// Kernel 2: flash attention (round-6 structure + T5 setprio + T13 defer-max)
// ---------------------------------------------------------------------------
__global__ __launch_bounds__(256, 2) void attn_fwd(
    const unsigned short* __restrict__ qk_ws,
    const unsigned short* __restrict__ vt_ws,
    const float* __restrict__ maskp,   // (B, S)
    float* __restrict__ out)           // (B, S, D)
{
    __shared__ unsigned short K_lds[2][64 * 64];
    __shared__ unsigned short V_lds[2][64 * 64];

    const int tid  = threadIdx.x;
    const int w    = tid >> 6, lane = tid & 63;
    const int hi   = lane >> 5, c32 = lane & 31;
    const int qt   = blockIdx.x & 15;
    const int bh   = blockIdx.x >> 4;
    const int b    = bh >> 4, h = bh & 15;

    const unsigned short* qp = qk_ws + (size_t)bh * (S_ * DH);
    const unsigned short* kp = qk_ws + QKSZ + (size_t)bh * (S_ * DH);
    const unsigned short* vp = vt_ws + (size_t)bh * (DH * S_);
    const float* mp = maskp + b * S_;

    const int q = qt * 128 + w * 32 + c32;

    short8 qf[4];
    #pragma unroll
    for (int ks = 0; ks < 4; ++ks)
        qf[ks] = *(const short8*)&qp[(size_t)q * DH + ks * 16 + 8 * hi];

    f32x16 ctx[2];
    #pragma unroll
    for (int d = 0; d < 2; ++d)
        #pragma unroll
        for (int r = 0; r < 16; ++r) ctx[d][r] = 0.f;
    float mrow = -1e30f, lsum = 0.f;

    ushort8 rk[2], rv[2];
    const int su0 = tid, su1 = tid + 256;

    auto LOADT = [&](int t) {
        const int kv = t * 64;
        {
            int row = su0 >> 3, c = (su0 & 7) * 8;
            rk[0] = *(const ushort8*)&kp[(size_t)(kv + row) * DH + c];
            rv[0] = *(const ushort8*)&vp[(size_t)row * S_ + kv + c];
        }
        {
            int row = su1 >> 3, c = (su1 & 7) * 8;
            rk[1] = *(const ushort8*)&kp[(size_t)(kv + row) * DH + c];
            rv[1] = *(const ushort8*)&vp[(size_t)row * S_ + kv + c];
        }
    };
    auto WRITET = [&](int buf) {
        {
            int row = su0 >> 3, c = (su0 & 7) * 16;
            int off = (row * 128 + c) ^ ((row & 7) << 4);
            *(ushort8*)((char*)&K_lds[buf][0] + off) = rk[0];
            *(ushort8*)((char*)&V_lds[buf][0] + off) = rv[0];
        }
        {
            int row = su1 >> 3, c = (su1 & 7) * 16;
            int off = (row * 128 + c) ^ ((row & 7) << 4);
            *(ushort8*)((char*)&K_lds[buf][0] + off) = rk[1];
            *(ushort8*)((char*)&V_lds[buf][0] + off) = rv[1];
        }
    };

    LOADT(0); WRITET(0); LOADT(1);
    __syncthreads();

    const int NT = S_ / 64;   // 32
    for (int t = 0; t < NT; ++t) {
        const int cur = t & 1;
        const int kv  = t * 64;
        const char* Kb = (const char*)&K_lds[cur][0];
        const char* Vb = (const char*)&V_lds[cur][0];

        f32x16 sa0, sa1;
        #pragma unroll
        for (int r = 0; r < 16; ++r) { sa0[r] = 0.f; sa1[r] = 0.f; }
        __builtin_amdgcn_s_setprio(1);
        #pragma unroll
        for (int ks = 0; ks < 4; ++ks) {
            const int colb = ks * 32 + hi * 16;
            short8 kf0 = *(const short8*)(Kb + ((c32 * 128 + colb) ^ ((c32 & 7) << 4)));
            short8 kf1 = *(const short8*)(Kb + (((32 + c32) * 128 + colb) ^ ((c32 & 7) << 4)));
            sa0 = __builtin_amdgcn_mfma_f32_32x32x16_bf16(kf0, qf[ks], sa0, 0, 0, 0);
            sa1 = __builtin_amdgcn_mfma_f32_32x32x16_bf16(kf1, qf[ks], sa1, 0, 0, 0);
        }
        __builtin_amdgcn_s_setprio(0);

        float sc0[16], sc1[16];
        #pragma unroll
        for (int r = 0; r < 16; ++r) {
            const int koff = (r & 3) + 8 * (r >> 2) + 4 * hi;
            sc0[r] = sa0[r] * 0.125f + mp[kv + koff];
            sc1[r] = sa1[r] * 0.125f + mp[kv + 32 + koff];
        }

        float pm = sc0[0];
        #pragma unroll
        for (int r = 1; r < 16; ++r) pm = fmaxf(pm, sc0[r]);
        #pragma unroll
        for (int r = 0; r < 16; ++r) pm = fmaxf(pm, sc1[r]);
        pm = fmaxf(pm, __shfl_xor(pm, 32));

        // T13 defer-max: only rescale when some row's max grew by > 8
        if (!__all(pm - mrow <= 8.0f)) {
            const float mnew = fmaxf(mrow, pm);
            const float fac  = __expf(mrow - mnew);
            mrow = mnew;
            lsum *= fac;
            #pragma unroll
            for (int d = 0; d < 2; ++d)
                #pragma unroll
                for (int r = 0; r < 16; ++r) ctx[d][r] *= fac;
        }

        float p0[16], p1[16];
        float ps = 0.f;
        #pragma unroll
        for (int r = 0; r < 16; ++r) { p0[r] = __expf(sc0[r] - mrow); ps += p0[r]; }
        #pragma unroll
        for (int r = 0; r < 16; ++r) { p1[r] = __expf(sc1[r] - mrow); ps += p1[r]; }
        lsum += ps;

        short8 pf[4];
        #pragma unroll
        for (int ks4 = 0; ks4 < 4; ++ks4) {
            const float* pp = (ks4 < 2) ? p0 : p1;
            const int k8 = (ks4 & 1) * 8;
            unsigned int a0 = ((unsigned int)f2bf(pp[k8 + 1]) << 16) | f2bf(pp[k8 + 0]);
            unsigned int a1 = ((unsigned int)f2bf(pp[k8 + 3]) << 16) | f2bf(pp[k8 + 2]);
            unsigned int b0 = ((unsigned int)f2bf(pp[k8 + 5]) << 16) | f2bf(pp[k8 + 4]);
            unsigned int b1 = ((unsigned int)f2bf(pp[k8 + 7]) << 16) | f2bf(pp[k8 + 6]);
            unsigned int ax0 = (unsigned int)__shfl_xor((int)a0, 32);
            unsigned int ax1 = (unsigned int)__shfl_xor((int)a1, 32);
            unsigned int bx0 = (unsigned int)__shfl_xor((int)b0, 32);
            unsigned int bx1 = (unsigned int)__shfl_xor((int)b1, 32);
            union { unsigned int u[4]; short8 v; } fr;
            fr.u[0] = hi ? bx0 : a0;
            fr.u[1] = hi ? bx1 : a1;
            fr.u[2] = hi ? b0  : ax0;
            fr.u[3] = hi ? b1  : ax1;
            pf[ks4] = fr.v;
        }

        if (t + 1 < NT) {
            __syncthreads();
            WRITET(cur ^ 1);
            if (t + 2 < NT) LOADT(t + 2);
        }

        __builtin_amdgcn_s_setprio(1);
        #pragma unroll
        for (int ks4 = 0; ks4 < 4; ++ks4) {
            const int colb = ks4 * 32 + hi * 16;
            short8 vf0 = *(const short8*)(Vb + ((c32 * 128 + colb) ^ ((c32 & 7) << 4)));
            short8 vf1 = *(const short8*)(Vb + (((32 + c32) * 128 + colb) ^ ((c32 & 7) << 4)));
            ctx[0] = __builtin_amdgcn_mfma_f32_32x32x16_bf16(vf0, pf[ks4], ctx[0], 0, 0, 0);
            ctx[1] = __builtin_amdgcn_mfma_f32_32x32x16_bf16(vf1, pf[ks4], ctx[1], 0, 0, 0);
        }
        __builtin_amdgcn_s_setprio(0);

        if (t + 1 < NT) __syncthreads();
    }

    const float inv = 1.0f / (lsum + __shfl_xor(lsum, 32));

    float* ob = out + ((size_t)(b * S_ + q) * D_) + h * DH;
    #pragma unroll
    for (int d = 0; d < 2; ++d)
        #pragma unroll
        for (int q4 = 0; q4 < 4; ++q4) {
            f32x4 st;
            st[0] = ctx[d][q4 * 4 + 0] * inv;
            st[1] = ctx[d][q4 * 4 + 1] * inv;
            st[2] = ctx[d][q4 * 4 + 2] * inv;
            st[3] = ctx[d][q4 * 4 + 3] * inv;
            *(f32x4*)&ob[d * 32 + 8 * q4 + 4 * hi] = st;
        }
}

extern "C" void kernel_launch(void* const* d_in, const int* in_sizes, int n_in,
                              void* d_out, int out_size, void* d_ws, size_t ws_size,
                              hipStream_t stream) {
    (void)in_sizes; (void)n_in; (void)out_size;
    const float* hid  = (const float*)d_in[0];
    const float* sp   = (const float*)d_in[1];
    const float* mask = (const float*)d_in[2];
    const float* Wq   = (const float*)d_in[3];
    const float* Wk   = (const float*)d_in[4];
    const float* Wv   = (const float*)d_in[5];
    float* out = (float*)d_out;

    unsigned short* qk_ws = (unsigned short*)d_ws;       // q (8MB) + k (8MB)
    unsigned short* vt_ws = qk_ws + 2 * (size_t)QKSZ;    // vT (8MB)
    unsigned short* hb    = vt_ws + (size_t)QKSZ;        // bf16 hid (8MB)
    unsigned short* wb    = hb + 4194304;                // bf16 W (6MB)

    const size_t NEED = 39845888;   // 38 MB
    if (ws_size >= NEED) {
        cvt_all<<<dim3(3584), dim3(256), 0, stream>>>(hid, Wq, Wk, Wv, hb, wb);
        qkv_gemm<<<dim3(32 * 24), dim3(256), 0, stream>>>(hb, wb, sp, qk_ws, vt_ws);
    } else {
        qkv_proj<<<dim3(32 * 24), dim3(256), 0, stream>>>(hid, sp, Wq, Wk, Wv, qk_ws, vt_ws);
    }
    attn_fwd<<<dim3(32 * 16), dim3(256), 0, stream>>>(qk_ws, vt_ws, mask, out);
}

// Round 8
// 185.848 us; speedup vs baseline: 4.2762x; 1.0611x over previous
//
#include <hip/hip_runtime.h>
#include <hip/hip_bf16.h>
#include <math.h>

#define B_  2
#define S_  2048
#define D_  1024
#define H_  16
#define DH  64
#define QKSZ 4194304    // B*H*S*DH

typedef __attribute__((ext_vector_type(4)))  float  f32x4;
typedef __attribute__((ext_vector_type(16))) float  f32x16;
typedef __attribute__((ext_vector_type(8)))  short  short8;
typedef __attribute__((ext_vector_type(8)))  unsigned short ushort8;
typedef __attribute__((ext_vector_type(4)))  unsigned short us4;

#define LOG2E 1.44269504f
#define QSCL  0.18033688f   // 0.125 * log2(e)

static __device__ __forceinline__ unsigned short f2bf(float x) {
    union { float f; unsigned int u; } v; v.f = x;
    unsigned int u = v.u;
    u += 0x7fffu + ((u >> 16) & 1u);   // RNE
    return (unsigned short)(u >> 16);
}

// packed bf16 pair via native conversion (compiler pairs to v_cvt_pk_bf16_f32)
static __device__ __forceinline__ unsigned int pk2(float lo, float hi) {
    union { __hip_bfloat162 b; unsigned int u; } c;
    c.b = __float22bfloat162_rn(float2{lo, hi});
    return c.u;
}

static __device__ __forceinline__ float exp2a(float x) {   // D = 2^x
    float r;
    asm("v_exp_f32 %0, %1" : "=v"(r) : "v"(x));
    return r;
}

typedef __attribute__((address_space(3))) void       lds_void;
typedef const __attribute__((address_space(1))) void gbl_void;

static __device__ __forceinline__ void gload_lds16(const unsigned short* g,
                                                   unsigned short* l) {
    __builtin_amdgcn_global_load_lds((gbl_void*)g, (lds_void*)l, 16, 0, 0);
}

// ---------------------------------------------------------------------------
// Kernel 0: fp32 -> bf16 pre-convert (hid 4M elems, then Wq|Wk|Wv 3M elems)
// ---------------------------------------------------------------------------
__global__ __launch_bounds__(256) void cvt_all(
    const float* __restrict__ hid, const float* __restrict__ Wq,
    const float* __restrict__ Wk,  const float* __restrict__ Wv,
    unsigned short* __restrict__ hb, unsigned short* __restrict__ wb)
{
    const size_t i = ((size_t)blockIdx.x * 256 + threadIdx.x) * 8;
    const float* s; unsigned short* d;
    if (i < 4194304) { s = hid + i; d = hb + i; }
    else {
        size_t j = i - 4194304;
        const float* w = (j < 1048576) ? Wq : (j < 2097152) ? Wk : Wv;
        s = w + (j & 1048575);
        d = wb + j;
    }
    float4 a = *(const float4*)s, b = *(const float4*)(s + 4);
    ushort8 o;
    o[0] = f2bf(a.x); o[1] = f2bf(a.y); o[2] = f2bf(a.z); o[3] = f2bf(a.w);
    o[4] = f2bf(b.x); o[5] = f2bf(b.y); o[6] = f2bf(b.z); o[7] = f2bf(b.w);
    *(ushort8*)d = o;
}

// ---------------------------------------------------------------------------
// Kernel 1: QKV GEMM. BK=64, global_load_lds(16B) with pre-swizzled source,
// swizzled frag reads (2-way banks), 128x128 tile, 4 waves, 32 MFMA/step.
// Fused RoPE; Q pre-scaled by 0.125*log2e (attn works in exp2 domain).
// ---------------------------------------------------------------------------
__global__ __launch_bounds__(256) void qkv_gemm(
    const unsigned short* __restrict__ hb,   // bf16 [4096][1024]
    const unsigned short* __restrict__ wb,   // bf16 [3072][1024] (Wq|Wk|Wv)
    const float* __restrict__ sp,            // (S,64): sin | cos
    unsigned short* __restrict__ qk_ws,
    unsigned short* __restrict__ vt_ws)
{
    __shared__ unsigned short As[128 * 64];   // 16 KB, rows of 128B, swizzled cols
    __shared__ unsigned short Bs[128 * 64];

    const int tid    = threadIdx.x;
    const int tile_m = (blockIdx.x & 31) * 128;
    const int tile_n = (blockIdx.x >> 5) * 128;

    const int w  = tid >> 6, lane = tid & 63;
    const int wr = w >> 1,  wc = w & 1;
    const int g  = lane >> 4, c16 = lane & 15;

    // staging: lane covers row (w*8 + rg), swizzled col granule cg = s ^ (row&7)
    const int rg = lane >> 3;                 // 0..7 (== row&7 since w*8%8==0)
    const int cg = (lane & 7) ^ rg;
    const size_t a_base = (size_t)(tile_m + w * 8 + rg) * 1024 + cg * 8;
    const size_t b_base = (size_t)(tile_n + w * 8 + rg) * 1024 + cg * 8;

    f32x4 acc[4][4];
    #pragma unroll
    for (int i = 0; i < 4; ++i)
        #pragma unroll
        for (int j = 0; j < 4; ++j)
            acc[i][j][0] = acc[i][j][1] = acc[i][j][2] = acc[i][j][3] = 0.f;

    for (int k0 = 0; k0 < 1024; k0 += 64) {
        #pragma unroll
        for (int p = 0; p < 4; ++p) {
            gload_lds16(hb + a_base + (size_t)p * 32768 + k0, &As[(p * 32 + w * 8) * 64]);
            gload_lds16(wb + b_base + (size_t)p * 32768 + k0, &Bs[(p * 32 + w * 8) * 64]);
        }
        __syncthreads();

        #pragma unroll
        for (int kk = 0; kk < 2; ++kk) {
            short8 af[4], bf[4];
            #pragma unroll
            for (int i = 0; i < 4; ++i) {
                const int row = wr * 64 + i * 16 + c16;
                af[i] = *(const short8*)&As[row * 64 + (((kk << 2) + g) ^ (row & 7)) * 8];
            }
            #pragma unroll
            for (int j = 0; j < 4; ++j) {
                const int row = wc * 64 + j * 16 + c16;
                bf[j] = *(const short8*)&Bs[row * 64 + (((kk << 2) + g) ^ (row & 7)) * 8];
            }
            __builtin_amdgcn_s_setprio(1);
            #pragma unroll
            for (int i = 0; i < 4; ++i)
                #pragma unroll
                for (int j = 0; j < 4; ++j)
                    acc[i][j] = __builtin_amdgcn_mfma_f32_16x16x32_bf16(
                        af[i], bf[j], acc[i][j], 0, 0, 0);
            __builtin_amdgcn_s_setprio(0);
        }
        __syncthreads();
    }

    // ---- epilogue: m = tile_m + wr*64 + i*16 + 4g + r ; n = tile_n + wc*64 + j*16 + c16
    if (tile_n < 2048) {
        const int isK = (tile_n >= 1024) ? 1 : 0;
        const float qscl = isK ? 1.0f : QSCL;
        unsigned short* qkb = qk_ws + (size_t)isK * QKSZ;
        const int head = ((tile_n - (isK ? 1024 : 0)) + wc * 64) >> 6;
        #pragma unroll
        for (int j = 0; j < 4; ++j) {
            const int dh = j * 16 + c16;
            const int p  = dh >> 1;
            const int odd = dh & 1;
            #pragma unroll
            for (int i = 0; i < 4; ++i) {
                #pragma unroll
                for (int r = 0; r < 4; ++r) {
                    const int m = tile_m + wr * 64 + i * 16 + 4 * g + r;
                    const int b = m >> 11, s = m & 2047;
                    float v    = acc[i][j][r];
                    float part = __shfl_xor(v, 1);
                    float sv = sp[s * 64 + p];
                    float cv = sp[s * 64 + 32 + p];
                    float o  = (odd ? (v * cv + part * sv) : (v * cv - part * sv)) * qscl;
                    qkb[((size_t)(b * H_ + head) * S_ + s) * DH + dh] = f2bf(o);
                }
            }
        }
    } else {
        const int head = (tile_n - 2048 + wc * 64) >> 6;
        #pragma unroll
        for (int j = 0; j < 4; ++j) {
            const int dh = j * 16 + c16;
            #pragma unroll
            for (int i = 0; i < 4; ++i) {
                const int m0 = tile_m + wr * 64 + i * 16 + 4 * g;
                const int b = m0 >> 11, s0 = m0 & 2047;
                us4 o;
                o[0] = f2bf(acc[i][j][0]); o[1] = f2bf(acc[i][j][1]);
                o[2] = f2bf(acc[i][j][2]); o[3] = f2bf(acc[i][j][3]);
                *(us4*)&vt_ws[((size_t)(b * H_ + head) * DH + dh) * S_ + s0] = o;
            }
        }
    }
}

// ---------------------------------------------------------------------------
// Kernel 2: flash attention, swapped-QK^T 32x32 MFMA, exp2-domain softmax.
// Q pre-scaled by 0.125*log2e; mask staged in LDS pre-scaled by log2e.
// ---------------------------------------------------------------------------
__global__ __launch_bounds__(256, 2) void attn_fwd(
    const unsigned short* __restrict__ qk_ws,
    const unsigned short* __restrict__ vt_ws,
    const float* __restrict__ maskp,   // (B, S)
    float* __restrict__ out)           // (B, S, D)
{
    __shared__ unsigned short K_lds[2][64 * 64];
    __shared__ unsigned short V_lds[2][64 * 64];
    __shared__ float M_lds[2048];      // mask * log2e

    const int tid  = threadIdx.x;
    const int w    = tid >> 6, lane = tid & 63;
    const int hi   = lane >> 5, c32 = lane & 31;
    const int qt   = blockIdx.x & 15;
    const int bh   = blockIdx.x >> 4;
    const int b    = bh >> 4, h = bh & 15;

    const unsigned short* qp = qk_ws + (size_t)bh * (S_ * DH);
    const unsigned short* kp = qk_ws + QKSZ + (size_t)bh * (S_ * DH);
    const unsigned short* vp = vt_ws + (size_t)bh * (DH * S_);
    const float* mp = maskp + b * S_;

    const int q = qt * 128 + w * 32 + c32;

    short8 qf[4];
    #pragma unroll
    for (int ks = 0; ks < 4; ++ks)
        qf[ks] = *(const short8*)&qp[(size_t)q * DH + ks * 16 + 8 * hi];

    f32x16 ctx[2];
    #pragma unroll
    for (int d = 0; d < 2; ++d)
        #pragma unroll
        for (int r = 0; r < 16; ++r) ctx[d][r] = 0.f;
    float mrow = -1e30f, lsum = 0.f;

    ushort8 rk[2], rv[2];
    const int su0 = tid, su1 = tid + 256;

    auto LOADT = [&](int t) {
        const int kv = t * 64;
        {
            int row = su0 >> 3, c = (su0 & 7) * 8;
            rk[0] = *(const ushort8*)&kp[(size_t)(kv + row) * DH + c];
            rv[0] = *(const ushort8*)&vp[(size_t)row * S_ + kv + c];
        }
        {
            int row = su1 >> 3, c = (su1 & 7) * 8;
            rk[1] = *(const ushort8*)&kp[(size_t)(kv + row) * DH + c];
            rv[1] = *(const ushort8*)&vp[(size_t)row * S_ + kv + c];
        }
    };
    auto WRITET = [&](int buf) {
        {
            int row = su0 >> 3, c = (su0 & 7) * 16;
            int off = (row * 128 + c) ^ ((row & 7) << 4);
            *(ushort8*)((char*)&K_lds[buf][0] + off) = rk[0];
            *(ushort8*)((char*)&V_lds[buf][0] + off) = rv[0];
        }
        {
            int row = su1 >> 3, c = (su1 & 7) * 16;
            int off = (row * 128 + c) ^ ((row & 7) << 4);
            *(ushort8*)((char*)&K_lds[buf][0] + off) = rk[1];
            *(ushort8*)((char*)&V_lds[buf][0] + off) = rv[1];
        }
    };

    LOADT(0); WRITET(0); LOADT(1);
    {   // stage mask * log2e (once)
        float4 ma = *(const float4*)&mp[tid * 8];
        float4 mb2 = *(const float4*)&mp[tid * 8 + 4];
        M_lds[tid * 8 + 0] = ma.x * LOG2E;  M_lds[tid * 8 + 1] = ma.y * LOG2E;
        M_lds[tid * 8 + 2] = ma.z * LOG2E;  M_lds[tid * 8 + 3] = ma.w * LOG2E;
        M_lds[tid * 8 + 4] = mb2.x * LOG2E; M_lds[tid * 8 + 5] = mb2.y * LOG2E;
        M_lds[tid * 8 + 6] = mb2.z * LOG2E; M_lds[tid * 8 + 7] = mb2.w * LOG2E;
    }
    __syncthreads();

    const int NT = S_ / 64;   // 32
    for (int t = 0; t < NT; ++t) {
        const int cur = t & 1;
        const int kv  = t * 64;
        const char* Kb = (const char*)&K_lds[cur][0];
        const char* Vb = (const char*)&V_lds[cur][0];

        f32x16 sa0, sa1;
        #pragma unroll
        for (int r = 0; r < 16; ++r) { sa0[r] = 0.f; sa1[r] = 0.f; }
        __builtin_amdgcn_s_setprio(1);
        #pragma unroll
        for (int ks = 0; ks < 4; ++ks) {
            const int colb = ks * 32 + hi * 16;
            short8 kf0 = *(const short8*)(Kb + ((c32 * 128 + colb) ^ ((c32 & 7) << 4)));
            short8 kf1 = *(const short8*)(Kb + (((32 + c32) * 128 + colb) ^ ((c32 & 7) << 4)));
            sa0 = __builtin_amdgcn_mfma_f32_32x32x16_bf16(kf0, qf[ks], sa0, 0, 0, 0);
            sa1 = __builtin_amdgcn_mfma_f32_32x32x16_bf16(kf1, qf[ks], sa1, 0, 0, 0);
        }
        __builtin_amdgcn_s_setprio(0);

        // exp2-domain scores: sc = sa + mask*log2e
        float sc0[16], sc1[16];
        #pragma unroll
        for (int r = 0; r < 16; ++r) {
            const int koff = (r & 3) + 8 * (r >> 2) + 4 * hi;
            sc0[r] = sa0[r] + M_lds[kv + koff];
            sc1[r] = sa1[r] + M_lds[kv + 32 + koff];
        }

        // tree max over this lane's 32 values, then cross-half
        float tm[8];
        #pragma unroll
        for (int r2 = 0; r2 < 8; ++r2)
            tm[r2] = fmaxf(fmaxf(sc0[r2 * 2], sc0[r2 * 2 + 1]),
                           fmaxf(sc1[r2 * 2], sc1[r2 * 2 + 1]));
        float pm = fmaxf(fmaxf(fmaxf(tm[0], tm[1]), fmaxf(tm[2], tm[3])),
                         fmaxf(fmaxf(tm[4], tm[5]), fmaxf(tm[6], tm[7])));
        pm = fmaxf(pm, __shfl_xor(pm, 32));

        // defer-max (T13), exp2 units: 8*log2e ~= 11.54
        if (!__all(pm - mrow <= 11.54f)) {
            const float mnew = fmaxf(mrow, pm);
            const float fac  = exp2a(mrow - mnew);
            mrow = mnew;
            lsum *= fac;
            #pragma unroll
            for (int d = 0; d < 2; ++d)
                #pragma unroll
                for (int r = 0; r < 16; ++r) ctx[d][r] *= fac;
        }

        float p0[16], p1[16];
        float ps = 0.f;
        #pragma unroll
        for (int r = 0; r < 16; ++r) { p0[r] = exp2a(sc0[r] - mrow); ps += p0[r]; }
        #pragma unroll
        for (int r = 0; r < 16; ++r) { p1[r] = exp2a(sc1[r] - mrow); ps += p1[r]; }
        lsum += ps;

        // pack P -> PV B-frags: cvt_pk pairs + cross-half shfl_xor(32)
        short8 pf[4];
        #pragma unroll
        for (int ks4 = 0; ks4 < 4; ++ks4) {
            const float* pp = (ks4 < 2) ? p0 : p1;
            const int k8 = (ks4 & 1) * 8;
            unsigned int a0 = pk2(pp[k8 + 0], pp[k8 + 1]);
            unsigned int a1 = pk2(pp[k8 + 2], pp[k8 + 3]);
            unsigned int b0 = pk2(pp[k8 + 4], pp[k8 + 5]);
            unsigned int b1 = pk2(pp[k8 + 6], pp[k8 + 7]);
            unsigned int ax0 = (unsigned int)__shfl_xor((int)a0, 32);
            unsigned int ax1 = (unsigned int)__shfl_xor((int)a1, 32);
            unsigned int bx0 = (unsigned int)__shfl_xor((int)b0, 32);
            unsigned int bx1 = (unsigned int)__shfl_xor((int)b1, 32);
            union { unsigned int u[4]; short8 v; } fr;
            fr.u[0] = hi ? bx0 : a0;
            fr.u[1] = hi ? bx1 : a1;
            fr.u[2] = hi ? b0  : ax0;
            fr.u[3] = hi ? b1  : ax1;
            pf[ks4] = fr.v;
        }

        if (t + 1 < NT) {
            __syncthreads();
            WRITET(cur ^ 1);
            if (t + 2 < NT) LOADT(t + 2);
        }

        __builtin_amdgcn_s_setprio(1);
        #pragma unroll
        for (int ks4 = 0; ks4 < 4; ++ks4) {
            const int colb = ks4 * 32 + hi * 16;
            short8 vf0 = *(const short8*)(Vb + ((c32 * 128 + colb) ^ ((c32 & 7) << 4)));
            short8 vf1 = *(const short8*)(Vb + (((32 + c32) * 128 + colb) ^ ((c32 & 7) << 4)));
            ctx[0] = __builtin_amdgcn_mfma_f32_32x32x16_bf16(vf0, pf[ks4], ctx[0], 0, 0, 0);
            ctx[1] = __builtin_amdgcn_mfma_f32_32x32x16_bf16(vf1, pf[ks4], ctx[1], 0, 0, 0);
        }
        __builtin_amdgcn_s_setprio(0);

        if (t + 1 < NT) __syncthreads();
    }

    const float inv = 1.0f / (lsum + __shfl_xor(lsum, 32));

    float* ob = out + ((size_t)(b * S_ + q) * D_) + h * DH;
    #pragma unroll
    for (int d = 0; d < 2; ++d)
        #pragma unroll
        for (int q4 = 0; q4 < 4; ++q4) {
            f32x4 st;
            st[0] = ctx[d][q4 * 4 + 0] * inv;
            st[1] = ctx[d][q4 * 4 + 1] * inv;
            st[2] = ctx[d][q4 * 4 + 2] * inv;
            st[3] = ctx[d][q4 * 4 + 3] * inv;
            *(f32x4*)&ob[d * 32 + 8 * q4 + 4 * hi] = st;
        }
}

// ---------------------------------------------------------------------------
// Fallback (ws-tight): reg-staged qkv projection (Q pre-scaled to match attn)
// ---------------------------------------------------------------------------
__global__ __launch_bounds__(256) void qkv_proj(
    const float* __restrict__ hid,
    const float* __restrict__ sp,
    const float* __restrict__ Wq,
    const float* __restrict__ Wk,
    const float* __restrict__ Wv,
    unsigned short* __restrict__ qk_ws,
    unsigned short* __restrict__ vt_ws)
{
    __shared__ unsigned short As[128 * 32];
    __shared__ unsigned short Bs[128 * 32];

    const int tid    = threadIdx.x;
    const int tile_m = (blockIdx.x & 31) * 128;
    const int tile_n = (blockIdx.x >> 5) * 128;

    const float* W; int nloc;
    if (tile_n < 1024)      { W = Wq; nloc = tile_n; }
    else if (tile_n < 2048) { W = Wk; nloc = tile_n - 1024; }
    else                    { W = Wv; nloc = tile_n - 2048; }

    const int w    = tid >> 6, lane = tid & 63;
    const int wr   = w >> 1,  wc   = w & 1;
    const int g    = lane >> 4, c16 = lane & 15;
    const int srow = tid >> 3;
    const int scol = (tid & 7) * 4;

    f32x4 acc[4][4];
    #pragma unroll
    for (int i = 0; i < 4; ++i)
        #pragma unroll
        for (int j = 0; j < 4; ++j)
            acc[i][j][0] = acc[i][j][1] = acc[i][j][2] = acc[i][j][3] = 0.f;

    for (int k0 = 0; k0 < 1024; k0 += 32) {
        #pragma unroll
        for (int p = 0; p < 4; ++p) {
            const int row = p * 32 + srow;
            float4 a = *(const float4*)&hid[(size_t)(tile_m + row) * 1024 + k0 + scol];
            float4 b = *(const float4*)&W  [(size_t)(nloc   + row) * 1024 + k0 + scol];
            us4 ap, bp;
            ap[0] = f2bf(a.x); ap[1] = f2bf(a.y); ap[2] = f2bf(a.z); ap[3] = f2bf(a.w);
            bp[0] = f2bf(b.x); bp[1] = f2bf(b.y); bp[2] = f2bf(b.z); bp[3] = f2bf(b.w);
            *(us4*)&As[p * 1024 + tid * 4] = ap;
            *(us4*)&Bs[p * 1024 + tid * 4] = bp;
        }
        __syncthreads();

        short8 af[4], bf[4];
        #pragma unroll
        for (int i = 0; i < 4; ++i)
            af[i] = *(const short8*)&As[(wr * 64 + i * 16 + c16) * 32 + g * 8];
        #pragma unroll
        for (int j = 0; j < 4; ++j)
            bf[j] = *(const short8*)&Bs[(wc * 64 + j * 16 + c16) * 32 + g * 8];
        #pragma unroll
        for (int i = 0; i < 4; ++i)
            #pragma unroll
            for (int j = 0; j < 4; ++j)
                acc[i][j] = __builtin_amdgcn_mfma_f32_16x16x32_bf16(
                    af[i], bf[j], acc[i][j], 0, 0, 0);
        __syncthreads();
    }

    if (tile_n < 2048) {
        const int isK = (tile_n >= 1024) ? 1 : 0;
        const float qscl = isK ? 1.0f : QSCL;
        unsigned short* qkb = qk_ws + (size_t)isK * QKSZ;
        const int head = ((tile_n - (isK ? 1024 : 0)) + wc * 64) >> 6;
        #pragma unroll
        for (int j = 0; j < 4; ++j) {
            const int dh = j * 16 + c16;
            const int p  = dh >> 1;
            const int odd = dh & 1;
            #pragma unroll
            for (int i = 0; i < 4; ++i) {
                #pragma unroll
                for (int r = 0; r < 4; ++r) {
                    const int m = tile_m + wr * 64 + i * 16 + 4 * g + r;
                    const int b = m >> 11, s = m & 2047;
                    float v    = acc[i][j][r];
                    float part = __shfl_xor(v, 1);
                    float sv = sp[s * 64 + p];
                    float cv = sp[s * 64 + 32 + p];
                    float o  = (odd ? (v * cv + part * sv) : (v * cv - part * sv)) * qscl;
                    qkb[((size_t)(b * H_ + head) * S_ + s) * DH + dh] = f2bf(o);
                }
            }
        }
    } else {
        const int head = (tile_n - 2048 + wc * 64) >> 6;
        #pragma unroll
        for (int j = 0; j < 4; ++j) {
            const int dh = j * 16 + c16;
            #pragma unroll
            for (int i = 0; i < 4; ++i) {
                const int m0 = tile_m + wr * 64 + i * 16 + 4 * g;
                const int b = m0 >> 11, s0 = m0 & 2047;
                us4 o;
                o[0] = f2bf(acc[i][j][0]); o[1] = f2bf(acc[i][j][1]);
                o[2] = f2bf(acc[i][j][2]); o[3] = f2bf(acc[i][j][3]);
                *(us4*)&vt_ws[((size_t)(b * H_ + head) * DH + dh) * S_ + s0] = o;
            }
        }
    }
}

extern "C" void kernel_launch(void* const* d_in, const int* in_sizes, int n_in,
                              void* d_out, int out_size, void* d_ws, size_t ws_size,
                              hipStream_t stream) {
    (void)in_sizes; (void)n_in; (void)out_size;
    const float* hid  = (const float*)d_in[0];
    const float* sp   = (const float*)d_in[1];
    const float* mask = (const float*)d_in[2];
    const float* Wq   = (const float*)d_in[3];
    const float* Wk   = (const float*)d_in[4];
    const float* Wv   = (const float*)d_in[5];
    float* out = (float*)d_out;

    unsigned short* qk_ws = (unsigned short*)d_ws;       // q (8MB) + k (8MB)
    unsigned short* vt_ws = qk_ws + 2 * (size_t)QKSZ;    // vT (8MB)
    unsigned short* hb    = vt_ws + (size_t)QKSZ;        // bf16 hid (8MB)
    unsigned short* wb    = hb + 4194304;                // bf16 W (6MB)

    const size_t NEED = 39845888;   // 38 MB
    if (ws_size >= NEED) {
        cvt_all<<<dim3(3584), dim3(256), 0, stream>>>(hid, Wq, Wk, Wv, hb, wb);
        qkv_gemm<<<dim3(32 * 24), dim3(256), 0, stream>>>(hb, wb, sp, qk_ws, vt_ws);
    } else {
        qkv_proj<<<dim3(32 * 24), dim3(256), 0, stream>>>(hid, sp, Wq, Wk, Wv, qk_ws, vt_ws);
    }
    attn_fwd<<<dim3(32 * 16), dim3(256), 0, stream>>>(qk_ws, vt_ws, mask, out);
}

// Round 9
// 185.435 us; speedup vs baseline: 4.2857x; 1.0022x over previous
//
#include <hip/hip_runtime.h>
#include <hip/hip_bf16.h>
#include <math.h>

#define B_  2
#define S_  2048
#define D_  1024
#define H_  16
#define DH  64
#define QKSZ 4194304    // B*H*S*DH

typedef __attribute__((ext_vector_type(4)))  float  f32x4;
typedef __attribute__((ext_vector_type(16))) float  f32x16;
typedef __attribute__((ext_vector_type(8)))  short  short8;
typedef __attribute__((ext_vector_type(8)))  unsigned short ushort8;
typedef __attribute__((ext_vector_type(4)))  unsigned short us4;

#define LOG2E 1.44269504f
#define QSCL  0.18033688f   // 0.125 * log2(e)

static __device__ __forceinline__ unsigned short f2bf(float x) {
    union { float f; unsigned int u; } v; v.f = x;
    unsigned int u = v.u;
    u += 0x7fffu + ((u >> 16) & 1u);   // RNE
    return (unsigned short)(u >> 16);
}

// packed bf16 pair via native conversion (compiler pairs to v_cvt_pk_bf16_f32)
static __device__ __forceinline__ unsigned int pk2(float lo, float hi) {
    union { __hip_bfloat162 b; unsigned int u; } c;
    c.b = __float22bfloat162_rn(float2{lo, hi});
    return c.u;
}

static __device__ __forceinline__ float exp2a(float x) {   // D = 2^x
    float r;
    asm("v_exp_f32 %0, %1" : "=v"(r) : "v"(x));
    return r;
}

typedef __attribute__((address_space(3))) void       lds_void;
typedef const __attribute__((address_space(1))) void gbl_void;

static __device__ __forceinline__ void gload_lds16(const unsigned short* g,
                                                   unsigned short* l) {
    __builtin_amdgcn_global_load_lds((gbl_void*)g, (lds_void*)l, 16, 0, 0);
}

// ---------------------------------------------------------------------------
// Kernel 0: fp32 -> bf16 pre-convert (hid 4M elems, then Wq|Wk|Wv 3M elems)
// ---------------------------------------------------------------------------
__global__ __launch_bounds__(256) void cvt_all(
    const float* __restrict__ hid, const float* __restrict__ Wq,
    const float* __restrict__ Wk,  const float* __restrict__ Wv,
    unsigned short* __restrict__ hb, unsigned short* __restrict__ wb)
{
    const size_t i = ((size_t)blockIdx.x * 256 + threadIdx.x) * 8;
    const float* s; unsigned short* d;
    if (i < 4194304) { s = hid + i; d = hb + i; }
    else {
        size_t j = i - 4194304;
        const float* w = (j < 1048576) ? Wq : (j < 2097152) ? Wk : Wv;
        s = w + (j & 1048575);
        d = wb + j;
    }
    float4 a = *(const float4*)s, b = *(const float4*)(s + 4);
    ushort8 o;
    o[0] = f2bf(a.x); o[1] = f2bf(a.y); o[2] = f2bf(a.z); o[3] = f2bf(a.w);
    o[4] = f2bf(b.x); o[5] = f2bf(b.y); o[6] = f2bf(b.z); o[7] = f2bf(b.w);
    *(ushort8*)d = o;
}

// ---------------------------------------------------------------------------
// Kernel 1: QKV GEMM. BK=64, global_load_lds(16B) pre-swizzled source,
// swizzled frag reads, 128x128 tile, 4 waves, 32 MFMA/step. Fused RoPE.
// XCD n-band swizzle: xcd=bid&7 owns n-tiles [3*xcd, 3*xcd+3) -> wb band
// (0.75MB) stays resident in that XCD's L2; same-m blocks temporally adjacent.
// ---------------------------------------------------------------------------
__global__ __launch_bounds__(256) void qkv_gemm(
    const unsigned short* __restrict__ hb,   // bf16 [4096][1024]
    const unsigned short* __restrict__ wb,   // bf16 [3072][1024] (Wq|Wk|Wv)
    const float* __restrict__ sp,            // (S,64): sin | cos
    unsigned short* __restrict__ qk_ws,
    unsigned short* __restrict__ vt_ws)
{
    __shared__ unsigned short As[128 * 64];   // 16 KB, rows of 128B, swizzled cols
    __shared__ unsigned short Bs[128 * 64];

    const int tid  = threadIdx.x;
    // XCD-band mapping (bijective over 768: bid = (m*3 + n%3)*8 + n/3)
    const int xcd  = blockIdx.x & 7;
    const int jj   = blockIdx.x >> 3;        // 0..95
    const int tile_n = (xcd * 3 + (jj % 3)) * 128;
    const int tile_m = (jj / 3) * 128;

    const int w  = tid >> 6, lane = tid & 63;
    const int wr = w >> 1,  wc = w & 1;
    const int g  = lane >> 4, c16 = lane & 15;

    // staging: lane covers row (w*8 + rg), swizzled col granule cg = s ^ (row&7)
    const int rg = lane >> 3;                 // 0..7
    const int cg = (lane & 7) ^ rg;
    const size_t a_base = (size_t)(tile_m + w * 8 + rg) * 1024 + cg * 8;
    const size_t b_base = (size_t)(tile_n + w * 8 + rg) * 1024 + cg * 8;

    f32x4 acc[4][4];
    #pragma unroll
    for (int i = 0; i < 4; ++i)
        #pragma unroll
        for (int j = 0; j < 4; ++j)
            acc[i][j][0] = acc[i][j][1] = acc[i][j][2] = acc[i][j][3] = 0.f;

    for (int k0 = 0; k0 < 1024; k0 += 64) {
        #pragma unroll
        for (int p = 0; p < 4; ++p) {
            gload_lds16(hb + a_base + (size_t)p * 32768 + k0, &As[(p * 32 + w * 8) * 64]);
            gload_lds16(wb + b_base + (size_t)p * 32768 + k0, &Bs[(p * 32 + w * 8) * 64]);
        }
        __syncthreads();

        #pragma unroll
        for (int kk = 0; kk < 2; ++kk) {
            short8 af[4], bf[4];
            #pragma unroll
            for (int i = 0; i < 4; ++i) {
                const int row = wr * 64 + i * 16 + c16;
                af[i] = *(const short8*)&As[row * 64 + (((kk << 2) + g) ^ (row & 7)) * 8];
            }
            #pragma unroll
            for (int j = 0; j < 4; ++j) {
                const int row = wc * 64 + j * 16 + c16;
                bf[j] = *(const short8*)&Bs[row * 64 + (((kk << 2) + g) ^ (row & 7)) * 8];
            }
            __builtin_amdgcn_s_setprio(1);
            #pragma unroll
            for (int i = 0; i < 4; ++i)
                #pragma unroll
                for (int j = 0; j < 4; ++j)
                    acc[i][j] = __builtin_amdgcn_mfma_f32_16x16x32_bf16(
                        af[i], bf[j], acc[i][j], 0, 0, 0);
            __builtin_amdgcn_s_setprio(0);
        }
        __syncthreads();
    }

    // ---- epilogue: m = tile_m + wr*64 + i*16 + 4g + r ; n = tile_n + wc*64 + j*16 + c16
    if (tile_n < 2048) {
        const int isK = (tile_n >= 1024) ? 1 : 0;
        const float qscl = isK ? 1.0f : QSCL;
        unsigned short* qkb = qk_ws + (size_t)isK * QKSZ;
        const int head = ((tile_n - (isK ? 1024 : 0)) + wc * 64) >> 6;
        #pragma unroll
        for (int j = 0; j < 4; ++j) {
            const int dh = j * 16 + c16;
            const int p  = dh >> 1;
            const int odd = dh & 1;
            #pragma unroll
            for (int i = 0; i < 4; ++i) {
                #pragma unroll
                for (int r = 0; r < 4; ++r) {
                    const int m = tile_m + wr * 64 + i * 16 + 4 * g + r;
                    const int b = m >> 11, s = m & 2047;
                    float v    = acc[i][j][r];
                    float part = __shfl_xor(v, 1);
                    float sv = sp[s * 64 + p];
                    float cv = sp[s * 64 + 32 + p];
                    float o  = (odd ? (v * cv + part * sv) : (v * cv - part * sv)) * qscl;
                    qkb[((size_t)(b * H_ + head) * S_ + s) * DH + dh] = f2bf(o);
                }
            }
        }
    } else {
        const int head = (tile_n - 2048 + wc * 64) >> 6;
        #pragma unroll
        for (int j = 0; j < 4; ++j) {
            const int dh = j * 16 + c16;
            #pragma unroll
            for (int i = 0; i < 4; ++i) {
                const int m0 = tile_m + wr * 64 + i * 16 + 4 * g;
                const int b = m0 >> 11, s0 = m0 & 2047;
                us4 o;
                o[0] = f2bf(acc[i][j][0]); o[1] = f2bf(acc[i][j][1]);
                o[2] = f2bf(acc[i][j][2]); o[3] = f2bf(acc[i][j][3]);
                *(us4*)&vt_ws[((size_t)(b * H_ + head) * DH + dh) * S_ + s0] = o;
            }
        }
    }
}

// ---------------------------------------------------------------------------
// Kernel 2: flash attention, swapped-QK^T 32x32 MFMA, exp2-domain softmax.
// SINGLE barrier per KV tile (pre-WRITET barrier proven redundant: within
// iter t, QK/PV read buf[cur] while WRITET writes buf[cur^1]; all reads of
// buf[cur^1] finished before the previous iteration's end-barrier).
// ---------------------------------------------------------------------------
__global__ __launch_bounds__(256, 2) void attn_fwd(
    const unsigned short* __restrict__ qk_ws,
    const unsigned short* __restrict__ vt_ws,
    const float* __restrict__ maskp,   // (B, S)
    float* __restrict__ out)           // (B, S, D)
{
    __shared__ unsigned short K_lds[2][64 * 64];
    __shared__ unsigned short V_lds[2][64 * 64];
    __shared__ float M_lds[2048];      // mask * log2e

    const int tid  = threadIdx.x;
    const int w    = tid >> 6, lane = tid & 63;
    const int hi   = lane >> 5, c32 = lane & 31;
    const int qt   = blockIdx.x & 15;
    const int bh   = blockIdx.x >> 4;
    const int b    = bh >> 4, h = bh & 15;

    const unsigned short* qp = qk_ws + (size_t)bh * (S_ * DH);
    const unsigned short* kp = qk_ws + QKSZ + (size_t)bh * (S_ * DH);
    const unsigned short* vp = vt_ws + (size_t)bh * (DH * S_);
    const float* mp = maskp + b * S_;

    const int q = qt * 128 + w * 32 + c32;

    short8 qf[4];
    #pragma unroll
    for (int ks = 0; ks < 4; ++ks)
        qf[ks] = *(const short8*)&qp[(size_t)q * DH + ks * 16 + 8 * hi];

    f32x16 ctx[2];
    #pragma unroll
    for (int d = 0; d < 2; ++d)
        #pragma unroll
        for (int r = 0; r < 16; ++r) ctx[d][r] = 0.f;
    float mrow = -1e30f, lsum = 0.f;

    ushort8 rk[2], rv[2];
    const int su0 = tid, su1 = tid + 256;

    auto LOADT = [&](int t) {
        const int kv = t * 64;
        {
            int row = su0 >> 3, c = (su0 & 7) * 8;
            rk[0] = *(const ushort8*)&kp[(size_t)(kv + row) * DH + c];
            rv[0] = *(const ushort8*)&vp[(size_t)row * S_ + kv + c];
        }
        {
            int row = su1 >> 3, c = (su1 & 7) * 8;
            rk[1] = *(const ushort8*)&kp[(size_t)(kv + row) * DH + c];
            rv[1] = *(const ushort8*)&vp[(size_t)row * S_ + kv + c];
        }
    };
    auto WRITET = [&](int buf) {
        {
            int row = su0 >> 3, c = (su0 & 7) * 16;
            int off = (row * 128 + c) ^ ((row & 7) << 4);
            *(ushort8*)((char*)&K_lds[buf][0] + off) = rk[0];
            *(ushort8*)((char*)&V_lds[buf][0] + off) = rv[0];
        }
        {
            int row = su1 >> 3, c = (su1 & 7) * 16;
            int off = (row * 128 + c) ^ ((row & 7) << 4);
            *(ushort8*)((char*)&K_lds[buf][0] + off) = rk[1];
            *(ushort8*)((char*)&V_lds[buf][0] + off) = rv[1];
        }
    };

    LOADT(0); WRITET(0); LOADT(1);
    {   // stage mask * log2e (once)
        float4 ma = *(const float4*)&mp[tid * 8];
        float4 mb2 = *(const float4*)&mp[tid * 8 + 4];
        M_lds[tid * 8 + 0] = ma.x * LOG2E;  M_lds[tid * 8 + 1] = ma.y * LOG2E;
        M_lds[tid * 8 + 2] = ma.z * LOG2E;  M_lds[tid * 8 + 3] = ma.w * LOG2E;
        M_lds[tid * 8 + 4] = mb2.x * LOG2E; M_lds[tid * 8 + 5] = mb2.y * LOG2E;
        M_lds[tid * 8 + 6] = mb2.z * LOG2E; M_lds[tid * 8 + 7] = mb2.w * LOG2E;
    }
    __syncthreads();

    const int NT = S_ / 64;   // 32
    for (int t = 0; t < NT; ++t) {
        const int cur = t & 1;
        const int kv  = t * 64;
        const char* Kb = (const char*)&K_lds[cur][0];
        const char* Vb = (const char*)&V_lds[cur][0];

        f32x16 sa0, sa1;
        #pragma unroll
        for (int r = 0; r < 16; ++r) { sa0[r] = 0.f; sa1[r] = 0.f; }
        __builtin_amdgcn_s_setprio(1);
        #pragma unroll
        for (int ks = 0; ks < 4; ++ks) {
            const int colb = ks * 32 + hi * 16;
            short8 kf0 = *(const short8*)(Kb + ((c32 * 128 + colb) ^ ((c32 & 7) << 4)));
            short8 kf1 = *(const short8*)(Kb + (((32 + c32) * 128 + colb) ^ ((c32 & 7) << 4)));
            sa0 = __builtin_amdgcn_mfma_f32_32x32x16_bf16(kf0, qf[ks], sa0, 0, 0, 0);
            sa1 = __builtin_amdgcn_mfma_f32_32x32x16_bf16(kf1, qf[ks], sa1, 0, 0, 0);
        }
        __builtin_amdgcn_s_setprio(0);

        // exp2-domain scores: sc = sa + mask*log2e
        float sc0[16], sc1[16];
        #pragma unroll
        for (int r = 0; r < 16; ++r) {
            const int koff = (r & 3) + 8 * (r >> 2) + 4 * hi;
            sc0[r] = sa0[r] + M_lds[kv + koff];
            sc1[r] = sa1[r] + M_lds[kv + 32 + koff];
        }

        // tree max over this lane's 32 values, then cross-half
        float tm[8];
        #pragma unroll
        for (int r2 = 0; r2 < 8; ++r2)
            tm[r2] = fmaxf(fmaxf(sc0[r2 * 2], sc0[r2 * 2 + 1]),
                           fmaxf(sc1[r2 * 2], sc1[r2 * 2 + 1]));
        float pm = fmaxf(fmaxf(fmaxf(tm[0], tm[1]), fmaxf(tm[2], tm[3])),
                         fmaxf(fmaxf(tm[4], tm[5]), fmaxf(tm[6], tm[7])));
        pm = fmaxf(pm, __shfl_xor(pm, 32));

        // defer-max (T13), exp2 units: 8*log2e ~= 11.54
        if (!__all(pm - mrow <= 11.54f)) {
            const float mnew = fmaxf(mrow, pm);
            const float fac  = exp2a(mrow - mnew);
            mrow = mnew;
            lsum *= fac;
            #pragma unroll
            for (int d = 0; d < 2; ++d)
                #pragma unroll
                for (int r = 0; r < 16; ++r) ctx[d][r] *= fac;
        }

        float p0[16], p1[16];
        float ps = 0.f;
        #pragma unroll
        for (int r = 0; r < 16; ++r) { p0[r] = exp2a(sc0[r] - mrow); ps += p0[r]; }
        #pragma unroll
        for (int r = 0; r < 16; ++r) { p1[r] = exp2a(sc1[r] - mrow); ps += p1[r]; }
        lsum += ps;

        // pack P -> PV B-frags: cvt_pk pairs + cross-half shfl_xor(32)
        short8 pf[4];
        #pragma unroll
        for (int ks4 = 0; ks4 < 4; ++ks4) {
            const float* pp = (ks4 < 2) ? p0 : p1;
            const int k8 = (ks4 & 1) * 8;
            unsigned int a0 = pk2(pp[k8 + 0], pp[k8 + 1]);
            unsigned int a1 = pk2(pp[k8 + 2], pp[k8 + 3]);
            unsigned int b0 = pk2(pp[k8 + 4], pp[k8 + 5]);
            unsigned int b1 = pk2(pp[k8 + 6], pp[k8 + 7]);
            unsigned int ax0 = (unsigned int)__shfl_xor((int)a0, 32);
            unsigned int ax1 = (unsigned int)__shfl_xor((int)a1, 32);
            unsigned int bx0 = (unsigned int)__shfl_xor((int)b0, 32);
            unsigned int bx1 = (unsigned int)__shfl_xor((int)b1, 32);
            union { unsigned int u[4]; short8 v; } fr;
            fr.u[0] = hi ? bx0 : a0;
            fr.u[1] = hi ? bx1 : a1;
            fr.u[2] = hi ? b0  : ax0;
            fr.u[3] = hi ? b1  : ax1;
            pf[ks4] = fr.v;
        }

        // stage next tile (no barrier needed: writes go to buf[cur^1], whose
        // readers all finished before the previous end-of-iter barrier)
        if (t + 1 < NT) {
            WRITET(cur ^ 1);
            if (t + 2 < NT) LOADT(t + 2);
        }

        __builtin_amdgcn_s_setprio(1);
        #pragma unroll
        for (int ks4 = 0; ks4 < 4; ++ks4) {
            const int colb = ks4 * 32 + hi * 16;
            short8 vf0 = *(const short8*)(Vb + ((c32 * 128 + colb) ^ ((c32 & 7) << 4)));
            short8 vf1 = *(const short8*)(Vb + (((32 + c32) * 128 + colb) ^ ((c32 & 7) << 4)));
            ctx[0] = __builtin_amdgcn_mfma_f32_32x32x16_bf16(vf0, pf[ks4], ctx[0], 0, 0, 0);
            ctx[1] = __builtin_amdgcn_mfma_f32_32x32x16_bf16(vf1, pf[ks4], ctx[1], 0, 0, 0);
        }
        __builtin_amdgcn_s_setprio(0);

        if (t + 1 < NT) __syncthreads();   // writes of tile t+1 visible
    }

    const float inv = 1.0f / (lsum + __shfl_xor(lsum, 32));

    float* ob = out + ((size_t)(b * S_ + q) * D_) + h * DH;
    #pragma unroll
    for (int d = 0; d < 2; ++d)
        #pragma unroll
        for (int q4 = 0; q4 < 4; ++q4) {
            f32x4 st;
            st[0] = ctx[d][q4 * 4 + 0] * inv;
            st[1] = ctx[d][q4 * 4 + 1] * inv;
            st[2] = ctx[d][q4 * 4 + 2] * inv;
            st[3] = ctx[d][q4 * 4 + 3] * inv;
            *(f32x4*)&ob[d * 32 + 8 * q4 + 4 * hi] = st;
        }
}

// ---------------------------------------------------------------------------
// Fallback (ws-tight): reg-staged qkv projection (Q pre-scaled to match attn)
// ---------------------------------------------------------------------------
__global__ __launch_bounds__(256) void qkv_proj(
    const float* __restrict__ hid,
    const float* __restrict__ sp,
    const float* __restrict__ Wq,
    const float* __restrict__ Wk,
    const float* __restrict__ Wv,
    unsigned short* __restrict__ qk_ws,
    unsigned short* __restrict__ vt_ws)
{
    __shared__ unsigned short As[128 * 32];
    __shared__ unsigned short Bs[128 * 32];

    const int tid    = threadIdx.x;
    const int tile_m = (blockIdx.x & 31) * 128;
    const int tile_n = (blockIdx.x >> 5) * 128;

    const float* W; int nloc;
    if (tile_n < 1024)      { W = Wq; nloc = tile_n; }
    else if (tile_n < 2048) { W = Wk; nloc = tile_n - 1024; }
    else                    { W = Wv; nloc = tile_n - 2048; }

    const int w    = tid >> 6, lane = tid & 63;
    const int wr   = w >> 1,  wc   = w & 1;
    const int g    = lane >> 4, c16 = lane & 15;
    const int srow = tid >> 3;
    const int scol = (tid & 7) * 4;

    f32x4 acc[4][4];
    #pragma unroll
    for (int i = 0; i < 4; ++i)
        #pragma unroll
        for (int j = 0; j < 4; ++j)
            acc[i][j][0] = acc[i][j][1] = acc[i][j][2] = acc[i][j][3] = 0.f;

    for (int k0 = 0; k0 < 1024; k0 += 32) {
        #pragma unroll
        for (int p = 0; p < 4; ++p) {
            const int row = p * 32 + srow;
            float4 a = *(const float4*)&hid[(size_t)(tile_m + row) * 1024 + k0 + scol];
            float4 b = *(const float4*)&W  [(size_t)(nloc   + row) * 1024 + k0 + scol];
            us4 ap, bp;
            ap[0] = f2bf(a.x); ap[1] = f2bf(a.y); ap[2] = f2bf(a.z); ap[3] = f2bf(a.w);
            bp[0] = f2bf(b.x); bp[1] = f2bf(b.y); bp[2] = f2bf(b.z); bp[3] = f2bf(b.w);
            *(us4*)&As[p * 1024 + tid * 4] = ap;
            *(us4*)&Bs[p * 1024 + tid * 4] = bp;
        }
        __syncthreads();

        short8 af[4], bf[4];
        #pragma unroll
        for (int i = 0; i < 4; ++i)
            af[i] = *(const short8*)&As[(wr * 64 + i * 16 + c16) * 32 + g * 8];
        #pragma unroll
        for (int j = 0; j < 4; ++j)
            bf[j] = *(const short8*)&Bs[(wc * 64 + j * 16 + c16) * 32 + g * 8];
        #pragma unroll
        for (int i = 0; i < 4; ++i)
            #pragma unroll
            for (int j = 0; j < 4; ++j)
                acc[i][j] = __builtin_amdgcn_mfma_f32_16x16x32_bf16(
                    af[i], bf[j], acc[i][j], 0, 0, 0);
        __syncthreads();
    }

    if (tile_n < 2048) {
        const int isK = (tile_n >= 1024) ? 1 : 0;
        const float qscl = isK ? 1.0f : QSCL;
        unsigned short* qkb = qk_ws + (size_t)isK * QKSZ;
        const int head = ((tile_n - (isK ? 1024 : 0)) + wc * 64) >> 6;
        #pragma unroll
        for (int j = 0; j < 4; ++j) {
            const int dh = j * 16 + c16;
            const int p  = dh >> 1;
            const int odd = dh & 1;
            #pragma unroll
            for (int i = 0; i < 4; ++i) {
                #pragma unroll
                for (int r = 0; r < 4; ++r) {
                    const int m = tile_m + wr * 64 + i * 16 + 4 * g + r;
                    const int b = m >> 11, s = m & 2047;
                    float v    = acc[i][j][r];
                    float part = __shfl_xor(v, 1);
                    float sv = sp[s * 64 + p];
                    float cv = sp[s * 64 + 32 + p];
                    float o  = (odd ? (v * cv + part * sv) : (v * cv - part * sv)) * qscl;
                    qkb[((size_t)(b * H_ + head) * S_ + s) * DH + dh] = f2bf(o);
                }
            }
        }
    } else {
        const int head = (tile_n - 2048 + wc * 64) >> 6;
        #pragma unroll
        for (int j = 0; j < 4; ++j) {
            const int dh = j * 16 + c16;
            #pragma unroll
            for (int i = 0; i < 4; ++i) {
                const int m0 = tile_m + wr * 64 + i * 16 + 4 * g;
                const int b = m0 >> 11, s0 = m0 & 2047;
                us4 o;
                o[0] = f2bf(acc[i][j][0]); o[1] = f2bf(acc[i][j][1]);
                o[2] = f2bf(acc[i][j][2]); o[3] = f2bf(acc[i][j][3]);
                *(us4*)&vt_ws[((size_t)(b * H_ + head) * DH + dh) * S_ + s0] = o;
            }
        }
    }
}

extern "C" void kernel_launch(void* const* d_in, const int* in_sizes, int n_in,
                              void* d_out, int out_size, void* d_ws, size_t ws_size,
                              hipStream_t stream) {
    (void)in_sizes; (void)n_in; (void)out_size;
    const float* hid  = (const float*)d_in[0];
    const float* sp   = (const float*)d_in[1];
    const float* mask = (const float*)d_in[2];
    const float* Wq   = (const float*)d_in[3];
    const float* Wk   = (const float*)d_in[4];
    const float* Wv   = (const float*)d_in[5];
    float* out = (float*)d_out;

    unsigned short* qk_ws = (unsigned short*)d_ws;       // q (8MB) + k (8MB)
    unsigned short* vt_ws = qk_ws + 2 * (size_t)QKSZ;    // vT (8MB)
    unsigned short* hb    = vt_ws + (size_t)QKSZ;        // bf16 hid (8MB)
    unsigned short* wb    = hb + 4194304;                // bf16 W (6MB)

    const size_t NEED = 39845888;   // 38 MB
    if (ws_size >= NEED) {
        cvt_all<<<dim3(3584), dim3(256), 0, stream>>>(hid, Wq, Wk, Wv, hb, wb);
        qkv_gemm<<<dim3(32 * 24), dim3(256), 0, stream>>>(hb, wb, sp, qk_ws, vt_ws);
    } else {
        qkv_proj<<<dim3(32 * 24), dim3(256), 0, stream>>>(hid, sp, Wq, Wk, Wv, qk_ws, vt_ws);
    }
    attn_fwd<<<dim3(32 * 16), dim3(256), 0, stream>>>(qk_ws, vt_ws, mask, out);
}